// Round 10
// baseline (612.556 us; speedup 1.0000x reference)
//
#include <hip/hip_runtime.h>
#include <hip/hip_bf16.h>
#include <stdint.h>

#define HID 128
#define NPART 8
#define NCHUNK 256
#define MCHUNK 4096   // edges per radixA block
#define LBITS 10      // local dst bits; bucket = dst>>LBITS
#define SBITS 22      // src bits in packed word (N must be <= 1<<22)

// ---------------- mask storage detection ----------------
__global__ void detect_mask_kernel(const unsigned char* __restrict__ p, int nbytes,
                                   int nfloat, int* __restrict__ flags) {
  int stride = blockDim.x * gridDim.x;
  for (int i = blockIdx.x * blockDim.x + threadIdx.x; i < nbytes; i += stride) {
    if ((i & 3) && p[i] != 0) { atomicOr(&flags[0], 1); break; }
  }
  const float* fp = (const float*)p;
  for (int i = blockIdx.x * blockDim.x + threadIdx.x; i < nfloat; i += stride) {
    float f = fp[i];
    if (!(f == 0.0f || f == 1.0f)) { atomicOr(&flags[1], 1); break; }
  }
}

__global__ void expand_mask_h0(const void* __restrict__ maskp, const float4* __restrict__ x4,
                               const int* __restrict__ flags, const float* __restrict__ dis,
                               float* __restrict__ maskout, float* __restrict__ cvec,
                               float4* __restrict__ h0s, int N) {
  int i = blockIdx.x * blockDim.x + threadIdx.x;
  if (i >= N) return;
  float m;
  if (flags[0] == 0)      m = (((const int*)maskp)[i] != 0) ? 1.f : 0.f;
  else if (flags[1] == 0) m = (((const float*)maskp)[i] != 0.f) ? 1.f : 0.f;
  else                    m = (((const unsigned char*)maskp)[i] != 0) ? 1.f : 0.f;
  maskout[i] = m;
  float4 xv = x4[i];
  float4 h0 = make_float4(m * xv.x, m * xv.y, m * xv.z, m * xv.w);
  float* cv = cvec + (size_t)i * 8;
  cv[4] = h0.x; cv[5] = h0.y; cv[6] = h0.z; cv[7] = h0.w;
  float d = dis[i];
  h0s[i] = make_float4(d * h0.x, d * h0.y, d * h0.z, d * h0.w);
}

// ---------------- CSR build: two-pass LDS-staged radix ----------------
__global__ void init_gcur_kernel(int* __restrict__ gcur, int n, int CAPB) {
  int i = blockIdx.x * blockDim.x + threadIdx.x;
  if (i < n) gcur[i] = i * CAPB;
}

__global__ void radixA_kernel(const int* __restrict__ src, const int* __restrict__ dst,
                              int* __restrict__ gcur, uint32_t* __restrict__ bdata,
                              int nbin, int CAPB, int E) {
  __shared__ uint32_t sv[MCHUNK];
  __shared__ uint16_t sb[MCHUNK];
  __shared__ int bcnt[1024], boff[1024], gbase[1024];
  __shared__ int wsum[4];
  int t = threadIdx.x;
  int base = blockIdx.x * MCHUNK;
  int m = E - base; if (m > MCHUNK) m = MCHUNK;
  for (int i = t; i < 1024; i += 256) bcnt[i] = 0;
  __syncthreads();
  uint32_t pk[16]; short bn[16];
#pragma unroll
  for (int j = 0; j < 16; j++) {
    int i = base + t + j * 256;
    if (i < base + m) {
      int d = __builtin_nontemporal_load(&dst[i]);
      int s = __builtin_nontemporal_load(&src[i]);
      int b = d >> LBITS;
      pk[j] = ((uint32_t)(d & ((1 << LBITS) - 1)) << SBITS) | (uint32_t)s;
      bn[j] = (short)b;
      atomicAdd(&bcnt[b], 1);
    } else bn[j] = -1;
  }
  __syncthreads();
  {
    int lane = t & 63, w = t >> 6, i0 = t * 4;
    int v0 = bcnt[i0], v1 = bcnt[i0 + 1], v2 = bcnt[i0 + 2], v3 = bcnt[i0 + 3];
    int ts = v0 + v1 + v2 + v3, sc = ts;
    for (int d = 1; d < 64; d <<= 1) { int x = __shfl_up(sc, d, 64); if (lane >= d) sc += x; }
    if (lane == 63) wsum[w] = sc;
    __syncthreads();
    int wo = 0;
    for (int k = 0; k < w; k++) wo += wsum[k];
    int excl = wo + sc - ts;
    boff[i0] = excl; boff[i0 + 1] = excl + v0;
    boff[i0 + 2] = excl + v0 + v1; boff[i0 + 3] = excl + v0 + v1 + v2;
  }
  __syncthreads();
  for (int i = t; i < nbin; i += 256) {
    int c = bcnt[i];
    gbase[i] = c ? atomicAdd(&gcur[i], c) : 0;
  }
  __syncthreads();
  for (int i = t; i < nbin; i += 256) bcnt[i] = boff[i];
  __syncthreads();
#pragma unroll
  for (int j = 0; j < 16; j++) {
    if (bn[j] >= 0) {
      int p = atomicAdd(&bcnt[bn[j]], 1);
      sv[p] = pk[j];
      sb[p] = (uint16_t)bn[j];
    }
  }
  __syncthreads();
  for (int i = t; i < m; i += 256) {
    int b = sb[i];
    int gp = gbase[b] + (i - boff[b]);
    if (gp < (b + 1) * CAPB) bdata[gp] = sv[i];
  }
}

// fused btot + scan (single block, nbin <= 1024)
__global__ void bucket_meta_kernel(const int* __restrict__ gcur, int* __restrict__ bstart,
                                   int nbin, int CAPB) {
  __shared__ int wsum[4];
  int t = threadIdx.x, lane = t & 63, w = t >> 6, i0 = t * 4;
  int v[4];
#pragma unroll
  for (int q = 0; q < 4; q++) {
    int i = i0 + q;
    int c = 0;
    if (i < nbin) {
      c = gcur[i] - i * CAPB;
      if (c > CAPB) c = CAPB;
    }
    v[q] = c;
  }
  int ts = v[0] + v[1] + v[2] + v[3], sc = ts;
  for (int d = 1; d < 64; d <<= 1) { int x = __shfl_up(sc, d, 64); if (lane >= d) sc += x; }
  if (lane == 63) wsum[w] = sc;
  __syncthreads();
  int wo = 0;
  for (int k = 0; k < w; k++) wo += wsum[k];
  int excl = wo + sc - ts;
  int e[4] = {excl, excl + v[0], excl + v[0] + v[1], excl + v[0] + v[1] + v[2]};
#pragma unroll
  for (int q = 0; q < 4; q++)
    if (i0 + q < nbin) bstart[i0 + q] = e[q];
  if (t == 255) bstart[nbin] = wo + sc;
}

__global__ void radixB_kernel(const uint32_t* __restrict__ bdata, const int* __restrict__ gcur,
                              const int* __restrict__ bstart, int CAPB,
                              int* __restrict__ off, float* __restrict__ dis,
                              int* __restrict__ csr, int N, int E) {
  __shared__ int cnt[1024], loff[1024];
  __shared__ int wsum[4];
  int b = blockIdx.x, t = threadIdx.x;
  int cb = gcur[b] - b * CAPB; if (cb > CAPB) cb = CAPB;
  int gb = bstart[b];
  const uint32_t* bd = bdata + (size_t)b * CAPB;
  for (int i = t; i < 1024; i += 256) cnt[i] = 0;
  __syncthreads();
  for (int i = t; i < cb; i += 256) atomicAdd(&cnt[bd[i] >> SBITS], 1);
  __syncthreads();
  {
    int lane = t & 63, w = t >> 6, i0 = t * 4;
    int v0 = cnt[i0], v1 = cnt[i0 + 1], v2 = cnt[i0 + 2], v3 = cnt[i0 + 3];
    int ts = v0 + v1 + v2 + v3, sc = ts;
    for (int d = 1; d < 64; d <<= 1) { int x = __shfl_up(sc, d, 64); if (lane >= d) sc += x; }
    if (lane == 63) wsum[w] = sc;
    __syncthreads();
    int wo = 0;
    for (int k = 0; k < w; k++) wo += wsum[k];
    int e0 = wo + sc - ts;
    int e1 = e0 + v0, e2 = e1 + v1, e3 = e2 + v2;
    loff[i0] = e0; loff[i0 + 1] = e1; loff[i0 + 2] = e2; loff[i0 + 3] = e3;
    int d0 = b * 1024 + i0;
    if (d0 + 0 < N) { off[d0 + 0] = gb + e0; dis[d0 + 0] = rsqrtf((float)v0 + 1.0f); }
    if (d0 + 1 < N) { off[d0 + 1] = gb + e1; dis[d0 + 1] = rsqrtf((float)v1 + 1.0f); }
    if (d0 + 2 < N) { off[d0 + 2] = gb + e2; dis[d0 + 2] = rsqrtf((float)v2 + 1.0f); }
    if (d0 + 3 < N) { off[d0 + 3] = gb + e3; dis[d0 + 3] = rsqrtf((float)v3 + 1.0f); }
  }
  if (b == 0 && t == 0) off[N] = E;
  __syncthreads();
  for (int i = t; i < 1024; i += 256) cnt[i] = loff[i];
  __syncthreads();
  for (int i = t; i < cb; i += 256) {
    uint32_t v = bd[i];
    int p = atomicAdd(&cnt[v >> SBITS], 1);
    csr[gb + p] = (int)(v & ((1u << SBITS) - 1));
  }
}

// ---------------- scan machinery (fallback path) ----------------
__global__ void scan1_kernel(const int* __restrict__ cnt, int* __restrict__ off,
                             int* __restrict__ bsum, float* __restrict__ dis, int N) {
  __shared__ int wsum[4];
  int t = threadIdx.x, lane = t & 63, w = t >> 6;
  int base = blockIdx.x * 1024 + t * 4;
  int v0 = (base + 0 < N) ? cnt[base + 0] : 0;
  int v1 = (base + 1 < N) ? cnt[base + 1] : 0;
  int v2 = (base + 2 < N) ? cnt[base + 2] : 0;
  int v3 = (base + 3 < N) ? cnt[base + 3] : 0;
  if (dis) {
    if (base + 0 < N) dis[base + 0] = rsqrtf((float)v0 + 1.0f);
    if (base + 1 < N) dis[base + 1] = rsqrtf((float)v1 + 1.0f);
    if (base + 2 < N) dis[base + 2] = rsqrtf((float)v2 + 1.0f);
    if (base + 3 < N) dis[base + 3] = rsqrtf((float)v3 + 1.0f);
  }
  int ts = v0 + v1 + v2 + v3;
  int sc = ts;
  for (int d = 1; d < 64; d <<= 1) {
    int x = __shfl_up(sc, d, 64);
    if (lane >= d) sc += x;
  }
  if (lane == 63) wsum[w] = sc;
  __syncthreads();
  int wo = 0;
  for (int i = 0; i < w; i++) wo += wsum[i];
  int excl = wo + sc - ts;
  if (base + 0 < N) off[base + 0] = excl;
  if (base + 1 < N) off[base + 1] = excl + v0;
  if (base + 2 < N) off[base + 2] = excl + v0 + v1;
  if (base + 3 < N) off[base + 3] = excl + v0 + v1 + v2;
  if (t == 255) bsum[blockIdx.x] = wo + sc;
}

__global__ void scan2_kernel(int* __restrict__ bsum, int nb) {
  if (threadIdx.x == 0 && blockIdx.x == 0) {
    int run = 0;
    for (int i = 0; i < nb; i++) { int v = bsum[i]; bsum[i] = run; run += v; }
  }
}

__global__ void scan3_kernel(int* __restrict__ off, const int* __restrict__ bsum,
                             int* __restrict__ cur, int N, int E) {
  int i = blockIdx.x * blockDim.x + threadIdx.x;
  if (i < N) {
    int o = off[i] + bsum[i >> 10];
    off[i] = o;
    if (cur) cur[i] = o;
  }
  if (i == 0) off[N] = E;
}

__global__ void hist_part_kernel(const int* __restrict__ dst, int* __restrict__ cnt,
                                 int E, int N) {
  int p = blockIdx.x & (NPART - 1);
  int chunk = blockIdx.x >> 3;
  int lo = (int)((long long)p * N / NPART);
  int hi = (int)((long long)(p + 1) * N / NPART);
  int stride = NCHUNK * 256;
  for (int e = chunk * 256 + threadIdx.x; e < E; e += stride) {
    int d = __builtin_nontemporal_load(&dst[e]);
    if (d >= lo && d < hi) atomicAdd(&cnt[d], 1);
  }
}

__global__ void fill_part_kernel(const int* __restrict__ src, const int* __restrict__ dst,
                                 int* __restrict__ cur, int* __restrict__ csr, int E, int N) {
  int p = blockIdx.x & (NPART - 1);
  int chunk = blockIdx.x >> 3;
  int lo = (int)((long long)p * N / NPART);
  int hi = (int)((long long)(p + 1) * N / NPART);
  int stride = NCHUNK * 256;
  for (int e = chunk * 256 + threadIdx.x; e < E; e += stride) {
    int d = __builtin_nontemporal_load(&dst[e]);
    if (d >= lo && d < hi) {
      int s = __builtin_nontemporal_load(&src[e]);
      int pos = atomicAdd(&cur[d], 1);
      csr[pos] = s;
    }
  }
}

// ---------------- layer 0 aggregation ----------------
__global__ void l0_agg_kernel(const float4* __restrict__ h0s, const float* __restrict__ dis,
                              const int* __restrict__ off, const int* __restrict__ csr,
                              float* __restrict__ cvec, int N) {
  int n = blockIdx.x * blockDim.x + threadIdx.x;
  if (n >= N) return;
  float4 a = h0s[n];
  int e0 = off[n], e1 = off[n + 1];
  int i = e0;
  for (; i < e1 && (i & 3); i++) {
    float4 v = h0s[csr[i]];
    a.x += v.x; a.y += v.y; a.z += v.z; a.w += v.w;
  }
  for (; i + 4 <= e1; i += 4) {
    int4 c = *(const int4*)&csr[i];
    float4 v0 = h0s[c.x], v1 = h0s[c.y], v2 = h0s[c.z], v3 = h0s[c.w];
    a.x += v0.x + v1.x + v2.x + v3.x;
    a.y += v0.y + v1.y + v2.y + v3.y;
    a.z += v0.z + v1.z + v2.z + v3.z;
    a.w += v0.w + v1.w + v2.w + v3.w;
  }
  for (; i < e1; i++) {
    float4 v = h0s[csr[i]];
    a.x += v.x; a.y += v.y; a.z += v.z; a.w += v.w;
  }
  float dn = dis[n];
  float* cv = cvec + (size_t)n * 8;
  cv[0] = dn * a.x; cv[1] = dn * a.y; cv[2] = dn * a.z; cv[3] = dn * a.w;
}

__global__ void l0_combine_kernel(const float* __restrict__ cvec, const float* __restrict__ W0,
                                  const float* __restrict__ b0, const float* __restrict__ resW,
                                  const float* __restrict__ resb, const float* __restrict__ dis,
                                  float* __restrict__ h1, __hip_bfloat16* __restrict__ hbout) {
  int idx = blockIdx.x * blockDim.x + threadIdx.x;
  int n = idx >> 7, c = idx & 127;
  const float* cv = cvec + (size_t)n * 8;
  float acc = b0[c] + resb[c];
#pragma unroll
  for (int k = 0; k < 4; k++) {
    acc += cv[k] * W0[k * HID + c];
    acc += cv[4 + k] * resW[k * HID + c];
  }
  float v = fmaxf(acc, 0.0f);
  h1[idx] = v;
  if (hbout) hbout[idx] = __float2bfloat16(dis[n] * v);
}

// ---------------- fused: agg(hb) -> LDS tile -> gemm + residual + relu ----------------
// Block: 256 threads, 64-node tile. Each of 4 waves gathers 16 nodes (f32 sums in LDS),
// then the whole block runs the register-tiled GEMM on the LDS tile.
#define ACC1(W) { a0 += __uint_as_float((W) << 16); a1 += __uint_as_float((W) & 0xffff0000u); }

__device__ __forceinline__ void gather_tile(const uint32_t* __restrict__ hb,
                                            const float* __restrict__ dis,
                                            const int* __restrict__ off,
                                            const int* __restrict__ csr,
                                            float* __restrict__ ash, int n0, int N) {
  int t = threadIdx.x, lane = t & 63, wv = t >> 6;
  for (int ln = wv * 16; ln < wv * 16 + 16; ln++) {
    int node = n0 + ln;
    float a0 = 0.f, a1 = 0.f;
    if (node < N) {
      uint32_t w = hb[(size_t)node * 64 + lane];
      a0 = __uint_as_float(w << 16);
      a1 = __uint_as_float(w & 0xffff0000u);
      int e0 = off[node], e1 = off[node + 1];
      int i = e0;
      for (; i < e1 && (i & 3); i++) {
        uint32_t ww = hb[(size_t)csr[i] * 64 + lane];
        ACC1(ww)
      }
      for (; i + 16 <= e1; i += 16) {
        int4 c0 = *(const int4*)&csr[i];
        int4 c1 = *(const int4*)&csr[i + 4];
        int4 c2 = *(const int4*)&csr[i + 8];
        int4 c3 = *(const int4*)&csr[i + 12];
        uint32_t w0 = hb[(size_t)c0.x * 64 + lane];
        uint32_t w1 = hb[(size_t)c0.y * 64 + lane];
        uint32_t w2 = hb[(size_t)c0.z * 64 + lane];
        uint32_t w3 = hb[(size_t)c0.w * 64 + lane];
        uint32_t w4 = hb[(size_t)c1.x * 64 + lane];
        uint32_t w5 = hb[(size_t)c1.y * 64 + lane];
        uint32_t w6 = hb[(size_t)c1.z * 64 + lane];
        uint32_t w7 = hb[(size_t)c1.w * 64 + lane];
        uint32_t w8 = hb[(size_t)c2.x * 64 + lane];
        uint32_t w9 = hb[(size_t)c2.y * 64 + lane];
        uint32_t wa = hb[(size_t)c2.z * 64 + lane];
        uint32_t wb = hb[(size_t)c2.w * 64 + lane];
        uint32_t wc = hb[(size_t)c3.x * 64 + lane];
        uint32_t wd = hb[(size_t)c3.y * 64 + lane];
        uint32_t we = hb[(size_t)c3.z * 64 + lane];
        uint32_t wf = hb[(size_t)c3.w * 64 + lane];
        ACC1(w0) ACC1(w1) ACC1(w2) ACC1(w3) ACC1(w4) ACC1(w5) ACC1(w6) ACC1(w7)
        ACC1(w8) ACC1(w9) ACC1(wa) ACC1(wb) ACC1(wc) ACC1(wd) ACC1(we) ACC1(wf)
      }
      for (; i + 4 <= e1; i += 4) {
        int4 c = *(const int4*)&csr[i];
        uint32_t w0 = hb[(size_t)c.x * 64 + lane];
        uint32_t w1 = hb[(size_t)c.y * 64 + lane];
        uint32_t w2 = hb[(size_t)c.z * 64 + lane];
        uint32_t w3 = hb[(size_t)c.w * 64 + lane];
        ACC1(w0) ACC1(w1) ACC1(w2) ACC1(w3)
      }
      for (; i < e1; i++) {
        uint32_t ww = hb[(size_t)csr[i] * 64 + lane];
        ACC1(ww)
      }
      float dn = dis[node];
      a0 *= dn; a1 *= dn;
    }
    *(float2*)&ash[ln * HID + 2 * lane] = make_float2(a0, a1);
  }
}

__global__ void agg_gemm_kernel(const uint32_t* __restrict__ hb, const float* __restrict__ dis,
                                const int* __restrict__ off, const int* __restrict__ csr,
                                const float* __restrict__ hres,
                                const float* __restrict__ W, const float* __restrict__ b,
                                float* __restrict__ hout, __hip_bfloat16* __restrict__ hbout,
                                int N) {
  __shared__ float ash[64 * HID];
  int t = threadIdx.x;
  int n0 = blockIdx.x * 64;
  gather_tile(hb, dis, off, csr, ash, n0, N);
  __syncthreads();
  int tc = t & 31;
  int tn = t >> 5;
  float acc[8][4];
#pragma unroll
  for (int j = 0; j < 8; j++)
#pragma unroll
    for (int q = 0; q < 4; q++) acc[j][q] = 0.0f;

  for (int k = 0; k < HID; k += 4) {
    float4 w0 = *(const float4*)&W[(k + 0) * HID + tc * 4];
    float4 w1 = *(const float4*)&W[(k + 1) * HID + tc * 4];
    float4 w2 = *(const float4*)&W[(k + 2) * HID + tc * 4];
    float4 w3 = *(const float4*)&W[(k + 3) * HID + tc * 4];
#pragma unroll
    for (int j = 0; j < 8; j++) {
      float4 a = *(const float4*)&ash[(tn * 8 + j) * HID + k];
      acc[j][0] += a.x * w0.x + a.y * w1.x + a.z * w2.x + a.w * w3.x;
      acc[j][1] += a.x * w0.y + a.y * w1.y + a.z * w2.y + a.w * w3.y;
      acc[j][2] += a.x * w0.z + a.y * w1.z + a.z * w2.z + a.w * w3.z;
      acc[j][3] += a.x * w0.w + a.y * w1.w + a.z * w2.w + a.w * w3.w;
    }
  }
  float4 bv = *(const float4*)&b[tc * 4];
#pragma unroll
  for (int j = 0; j < 8; j++) {
    int gn = n0 + tn * 8 + j;
    if (gn < N) {
      float4 hv = *(const float4*)&hres[(size_t)gn * HID + tc * 4];
      float4 o;
      o.x = fmaxf(acc[j][0] + bv.x + hv.x, 0.0f);
      o.y = fmaxf(acc[j][1] + bv.y + hv.y, 0.0f);
      o.z = fmaxf(acc[j][2] + bv.z + hv.z, 0.0f);
      o.w = fmaxf(acc[j][3] + bv.w + hv.w, 0.0f);
      *(float4*)&hout[(size_t)gn * HID + tc * 4] = o;
      float dnn = dis[gn];
      __hip_bfloat162 p01 = __float22bfloat162_rn(make_float2(dnn * o.x, dnn * o.y));
      __hip_bfloat162 p23 = __float22bfloat162_rn(make_float2(dnn * o.z, dnn * o.w));
      *(__hip_bfloat162*)&hbout[(size_t)gn * HID + tc * 4] = p01;
      *(__hip_bfloat162*)&hbout[(size_t)gn * HID + tc * 4 + 2] = p23;
    }
  }
}

// layer-2 variant: epilogue computes out = relu(...)@fcW + fcb; h3 never leaves the block
__global__ void agg_gemm_fc_kernel(const uint32_t* __restrict__ hb, const float* __restrict__ dis,
                                   const int* __restrict__ off, const int* __restrict__ csr,
                                   const float* __restrict__ hres,
                                   const float* __restrict__ W, const float* __restrict__ b,
                                   const float* __restrict__ fcW, const float* __restrict__ fcb,
                                   float* __restrict__ out, int N) {
  __shared__ float ash[64 * HID];
  int t = threadIdx.x;
  int n0 = blockIdx.x * 64;
  gather_tile(hb, dis, off, csr, ash, n0, N);
  __syncthreads();
  int tc = t & 31;
  int tn = t >> 5;
  float acc[8][4];
#pragma unroll
  for (int j = 0; j < 8; j++)
#pragma unroll
    for (int q = 0; q < 4; q++) acc[j][q] = 0.0f;

  for (int k = 0; k < HID; k += 4) {
    float4 w0 = *(const float4*)&W[(k + 0) * HID + tc * 4];
    float4 w1 = *(const float4*)&W[(k + 1) * HID + tc * 4];
    float4 w2 = *(const float4*)&W[(k + 2) * HID + tc * 4];
    float4 w3 = *(const float4*)&W[(k + 3) * HID + tc * 4];
#pragma unroll
    for (int j = 0; j < 8; j++) {
      float4 a = *(const float4*)&ash[(tn * 8 + j) * HID + k];
      acc[j][0] += a.x * w0.x + a.y * w1.x + a.z * w2.x + a.w * w3.x;
      acc[j][1] += a.x * w0.y + a.y * w1.y + a.z * w2.y + a.w * w3.y;
      acc[j][2] += a.x * w0.z + a.y * w1.z + a.z * w2.z + a.w * w3.z;
      acc[j][3] += a.x * w0.w + a.y * w1.w + a.z * w2.w + a.w * w3.w;
    }
  }
  float4 f0 = *(const float4*)&fcW[(tc * 4 + 0) * 4];
  float4 f1 = *(const float4*)&fcW[(tc * 4 + 1) * 4];
  float4 f2 = *(const float4*)&fcW[(tc * 4 + 2) * 4];
  float4 f3 = *(const float4*)&fcW[(tc * 4 + 3) * 4];
  float4 bv = *(const float4*)&b[tc * 4];
  float4 fb = *(const float4*)&fcb[0];
#pragma unroll
  for (int j = 0; j < 8; j++) {
    int gn = n0 + tn * 8 + j;
    float4 o = make_float4(0.f, 0.f, 0.f, 0.f);
    if (gn < N) {
      float4 hv = *(const float4*)&hres[(size_t)gn * HID + tc * 4];
      o.x = fmaxf(acc[j][0] + bv.x + hv.x, 0.0f);
      o.y = fmaxf(acc[j][1] + bv.y + hv.y, 0.0f);
      o.z = fmaxf(acc[j][2] + bv.z + hv.z, 0.0f);
      o.w = fmaxf(acc[j][3] + bv.w + hv.w, 0.0f);
    }
    float r0 = o.x * f0.x + o.y * f1.x + o.z * f2.x + o.w * f3.x;
    float r1 = o.x * f0.y + o.y * f1.y + o.z * f2.y + o.w * f3.y;
    float r2 = o.x * f0.z + o.y * f1.z + o.z * f2.z + o.w * f3.z;
    float r3 = o.x * f0.w + o.y * f1.w + o.z * f2.w + o.w * f3.w;
#pragma unroll
    for (int d = 1; d < 32; d <<= 1) {
      r0 += __shfl_xor(r0, d, 64);
      r1 += __shfl_xor(r1, d, 64);
      r2 += __shfl_xor(r2, d, 64);
      r3 += __shfl_xor(r3, d, 64);
    }
    if (tc == 0 && gn < N)
      *(float4*)&out[(size_t)gn * 4] =
          make_float4(r0 + fb.x, r1 + fb.y, r2 + fb.z, r3 + fb.w);
  }
}

// ---------------- f32 fallback kernels (ws too small for bf16 buffers) ----------------
__global__ void agg_hid_kernel(const float* __restrict__ h, const float* __restrict__ dis,
                               const int* __restrict__ off, const int* __restrict__ csr,
                               float* __restrict__ out, int N) {
  int node = blockIdx.x * 4 + (threadIdx.x >> 6);
  int lane = threadIdx.x & 63;
  if (node >= N) return;
  float dn = dis[node];
  const float* hrow = h + (size_t)node * HID;
  float a0 = dn * hrow[lane];
  float a1 = dn * hrow[lane + 64];
  int e0 = off[node], e1 = off[node + 1];
  for (int i = e0; i < e1; i++) {
    int s = csr[i];
    float d = dis[s];
    const float* hs = h + (size_t)s * HID;
    a0 += d * hs[lane];
    a1 += d * hs[lane + 64];
  }
  out[(size_t)node * HID + lane] = dn * a0;
  out[(size_t)node * HID + lane + 64] = dn * a1;
}

__global__ void gemm_resid_relu_kernel(const float* __restrict__ ag, float* __restrict__ hout,
                                       const float* __restrict__ hres,
                                       const float* __restrict__ W, const float* __restrict__ b,
                                       int N) {
  __shared__ float ash[64 * HID];
  int t = threadIdx.x;
  int n0 = blockIdx.x * 64;
  for (int i = t; i < 64 * HID; i += 256) {
    int gn = n0 + (i >> 7);
    ash[i] = (gn < N) ? ag[(size_t)gn * HID + (i & 127)] : 0.0f;
  }
  __syncthreads();
  int tc = t & 31;
  int tn = t >> 5;
  float acc[8][4];
#pragma unroll
  for (int j = 0; j < 8; j++)
#pragma unroll
    for (int q = 0; q < 4; q++) acc[j][q] = 0.0f;
  for (int k = 0; k < HID; k += 4) {
    float4 w0 = *(const float4*)&W[(k + 0) * HID + tc * 4];
    float4 w1 = *(const float4*)&W[(k + 1) * HID + tc * 4];
    float4 w2 = *(const float4*)&W[(k + 2) * HID + tc * 4];
    float4 w3 = *(const float4*)&W[(k + 3) * HID + tc * 4];
#pragma unroll
    for (int j = 0; j < 8; j++) {
      float4 a = *(const float4*)&ash[(tn * 8 + j) * HID + k];
      acc[j][0] += a.x * w0.x + a.y * w1.x + a.z * w2.x + a.w * w3.x;
      acc[j][1] += a.x * w0.y + a.y * w1.y + a.z * w2.y + a.w * w3.y;
      acc[j][2] += a.x * w0.z + a.y * w1.z + a.z * w2.z + a.w * w3.z;
      acc[j][3] += a.x * w0.w + a.y * w1.w + a.z * w2.w + a.w * w3.w;
    }
  }
  float4 bv = *(const float4*)&b[tc * 4];
#pragma unroll
  for (int j = 0; j < 8; j++) {
    int gn = n0 + tn * 8 + j;
    if (gn < N) {
      float4 hv = *(const float4*)&hres[(size_t)gn * HID + tc * 4];
      float4 o;
      o.x = fmaxf(acc[j][0] + bv.x + hv.x, 0.0f);
      o.y = fmaxf(acc[j][1] + bv.y + hv.y, 0.0f);
      o.z = fmaxf(acc[j][2] + bv.z + hv.z, 0.0f);
      o.w = fmaxf(acc[j][3] + bv.w + hv.w, 0.0f);
      *(float4*)&hout[(size_t)gn * HID + tc * 4] = o;
    }
  }
}

__global__ void gemm_resid_fc_kernel(const float* __restrict__ ag,
                                     const float* __restrict__ hres,
                                     const float* __restrict__ W, const float* __restrict__ b,
                                     const float* __restrict__ fcW, const float* __restrict__ fcb,
                                     float* __restrict__ out, int N) {
  __shared__ float ash[64 * HID];
  int t = threadIdx.x;
  int n0 = blockIdx.x * 64;
  for (int i = t; i < 64 * HID; i += 256) {
    int gn = n0 + (i >> 7);
    ash[i] = (gn < N) ? ag[(size_t)gn * HID + (i & 127)] : 0.0f;
  }
  __syncthreads();
  int tc = t & 31;
  int tn = t >> 5;
  float acc[8][4];
#pragma unroll
  for (int j = 0; j < 8; j++)
#pragma unroll
    for (int q = 0; q < 4; q++) acc[j][q] = 0.0f;
  for (int k = 0; k < HID; k += 4) {
    float4 w0 = *(const float4*)&W[(k + 0) * HID + tc * 4];
    float4 w1 = *(const float4*)&W[(k + 1) * HID + tc * 4];
    float4 w2 = *(const float4*)&W[(k + 2) * HID + tc * 4];
    float4 w3 = *(const float4*)&W[(k + 3) * HID + tc * 4];
#pragma unroll
    for (int j = 0; j < 8; j++) {
      float4 a = *(const float4*)&ash[(tn * 8 + j) * HID + k];
      acc[j][0] += a.x * w0.x + a.y * w1.x + a.z * w2.x + a.w * w3.x;
      acc[j][1] += a.x * w0.y + a.y * w1.y + a.z * w2.y + a.w * w3.y;
      acc[j][2] += a.x * w0.z + a.y * w1.z + a.z * w2.z + a.w * w3.z;
      acc[j][3] += a.x * w0.w + a.y * w1.w + a.z * w2.w + a.w * w3.w;
    }
  }
  float4 f0 = *(const float4*)&fcW[(tc * 4 + 0) * 4];
  float4 f1 = *(const float4*)&fcW[(tc * 4 + 1) * 4];
  float4 f2 = *(const float4*)&fcW[(tc * 4 + 2) * 4];
  float4 f3 = *(const float4*)&fcW[(tc * 4 + 3) * 4];
  float4 bv = *(const float4*)&b[tc * 4];
  float4 fb = *(const float4*)&fcb[0];
#pragma unroll
  for (int j = 0; j < 8; j++) {
    int gn = n0 + tn * 8 + j;
    float4 o = make_float4(0.f, 0.f, 0.f, 0.f);
    if (gn < N) {
      float4 hv = *(const float4*)&hres[(size_t)gn * HID + tc * 4];
      o.x = fmaxf(acc[j][0] + bv.x + hv.x, 0.0f);
      o.y = fmaxf(acc[j][1] + bv.y + hv.y, 0.0f);
      o.z = fmaxf(acc[j][2] + bv.z + hv.z, 0.0f);
      o.w = fmaxf(acc[j][3] + bv.w + hv.w, 0.0f);
    }
    float r0 = o.x * f0.x + o.y * f1.x + o.z * f2.x + o.w * f3.x;
    float r1 = o.x * f0.y + o.y * f1.y + o.z * f2.y + o.w * f3.y;
    float r2 = o.x * f0.z + o.y * f1.z + o.z * f2.z + o.w * f3.z;
    float r3 = o.x * f0.w + o.y * f1.w + o.z * f2.w + o.w * f3.w;
#pragma unroll
    for (int d = 1; d < 32; d <<= 1) {
      r0 += __shfl_xor(r0, d, 64);
      r1 += __shfl_xor(r1, d, 64);
      r2 += __shfl_xor(r2, d, 64);
      r3 += __shfl_xor(r3, d, 64);
    }
    if (tc == 0 && gn < N)
      *(float4*)&out[(size_t)gn * 4] =
          make_float4(r0 + fb.x, r1 + fb.y, r2 + fb.z, r3 + fb.w);
  }
}

// ---------------- host ----------------
extern "C" void kernel_launch(void* const* d_in, const int* in_sizes, int n_in,
                              void* d_out, int out_size, void* d_ws, size_t ws_size,
                              hipStream_t stream) {
  const float* x = (const float*)d_in[0];
  const int* edge = (const int*)d_in[1];
  const void* maskp = d_in[2];
  const float* W0 = (const float*)d_in[3];
  const float* b0 = (const float*)d_in[4];
  const float* resW = (const float*)d_in[5];
  const float* resb = (const float*)d_in[6];
  const float* W1 = (const float*)d_in[7];
  const float* b1 = (const float*)d_in[8];
  const float* W2 = (const float*)d_in[9];
  const float* b2 = (const float*)d_in[10];
  const float* fcW = (const float*)d_in[11];
  const float* fcb = (const float*)d_in[12];
  float* out = (float*)d_out;

  int N = in_sizes[0] / 4;
  int E = in_sizes[1] / 2;
  const int* srcp = edge;
  const int* dstp = edge + E;

  char* ws = (char*)d_ws;
  size_t cursor = 0;
  auto alloc = [&](size_t bytes) { char* p = ws + cursor; cursor += (bytes + 511) & ~(size_t)511; return p; };
  int* flags = (int*)alloc(16);
  int* cnt = (int*)alloc((size_t)N * 4);   // fallback path only
  float* dis = (float*)alloc((size_t)N * 4);
  int* off = (int*)alloc((size_t)(N + 1) * 4);
  int* bsum = (int*)alloc(1024);
  int nbin = (N + 1023) >> 10;
  int* gcur = (int*)alloc((size_t)(nbin + 1) * 4);
  int* bstart = (int*)alloc((size_t)(nbin + 1) * 4);
  int* csr = (int*)alloc((size_t)E * 4);
  float* h0s = (float*)alloc((size_t)N * 4 * 4);
  float* cvec = (float*)alloc((size_t)N * 8 * 4);
  float* buf0 = (float*)alloc((size_t)N * HID * 4);
  float* buf1 = (float*)alloc((size_t)N * HID * 4);
  size_t base_cursor = cursor;
  __hip_bfloat16* hb1 = (__hip_bfloat16*)alloc((size_t)N * HID * 2);
  __hip_bfloat16* hb2 = (__hip_bfloat16*)alloc((size_t)N * HID * 2);
  bool use_bf16 = (cursor <= ws_size);
  if (!use_bf16) {
    hb1 = nullptr; hb2 = nullptr;
    if (base_cursor > ws_size) return;
  }

  long long expect = (long long)E / (nbin > 0 ? nbin : 1);
  int CAPB = (int)((((expect * 5) / 4 + 127) / 64) * 64);
  if (CAPB < 256) CAPB = 256;
  size_t bdata_bytes = (size_t)nbin * CAPB * 4;
  bool use_radix = (N <= (1 << SBITS)) && (nbin <= 1024) &&
                   (bdata_bytes <= (size_t)N * HID * 4);
  uint32_t* bdata = (uint32_t*)buf1;  // staging aliases buf1 (dead until layer-1 gemm writes)

  int nThreadsN = (N + 255) / 256;
  int ngemm = (N + 63) / 64;

  hipMemsetAsync(flags, 0, 16, stream);
  detect_mask_kernel<<<256, 256, 0, stream>>>((const unsigned char*)maskp, N, N / 4, flags);

  if (use_radix) {
    init_gcur_kernel<<<(nbin + 255) / 256, 256, 0, stream>>>(gcur, nbin, CAPB);
    radixA_kernel<<<(E + MCHUNK - 1) / MCHUNK, 256, 0, stream>>>(srcp, dstp, gcur, bdata,
                                                                 nbin, CAPB, E);
    bucket_meta_kernel<<<1, 256, 0, stream>>>(gcur, bstart, nbin, CAPB);
    radixB_kernel<<<nbin, 256, 0, stream>>>(bdata, gcur, bstart, CAPB, off, dis, csr, N, E);
  } else {
    hipMemsetAsync(cnt, 0, (size_t)N * 4, stream);
    int nb = (N + 1023) / 1024;
    hist_part_kernel<<<NPART * NCHUNK, 256, 0, stream>>>(dstp, cnt, E, N);
    scan1_kernel<<<nb, 256, 0, stream>>>(cnt, off, bsum, dis, N);
    scan2_kernel<<<1, 64, 0, stream>>>(bsum, nb);
    scan3_kernel<<<nThreadsN, 256, 0, stream>>>(off, bsum, cnt, N, E);
    fill_part_kernel<<<NPART * NCHUNK, 256, 0, stream>>>(srcp, dstp, cnt, csr, E, N);
  }

  expand_mask_h0<<<nThreadsN, 256, 0, stream>>>(maskp, (const float4*)x, flags, dis,
                                                out + (size_t)N * 4, cvec, (float4*)h0s, N);

  // layer 0
  l0_agg_kernel<<<nThreadsN, 256, 0, stream>>>((const float4*)h0s, dis, off, csr, cvec, N);
  l0_combine_kernel<<<(N * HID + 255) / 256, 256, 0, stream>>>(cvec, W0, b0, resW, resb, dis,
                                                               buf0, hb1);

  if (use_bf16) {
    // layer 1 fused: gather(hb1) -> LDS -> gemm+res+relu -> buf1 (h2) + hb2
    agg_gemm_kernel<<<ngemm, 256, 0, stream>>>((const uint32_t*)hb1, dis, off, csr,
                                               buf0, W1, b1, buf1, hb2, N);
    // layer 2 fused: gather(hb2) -> LDS -> gemm+res+relu+fc -> out
    agg_gemm_fc_kernel<<<ngemm, 256, 0, stream>>>((const uint32_t*)hb2, dis, off, csr,
                                                  buf1, W2, b2, fcW, fcb, out, N);
  } else {
    // f32 fallback: separate agg + gemm, cvec as scratch? (buf-ping-pong as before)
    agg_hid_kernel<<<(N + 3) / 4, 256, 0, stream>>>(buf0, dis, off, csr, buf1, N);
    gemm_resid_relu_kernel<<<ngemm, 256, 0, stream>>>(buf1, buf1, buf0, W1, b1, N);
    agg_hid_kernel<<<(N + 3) / 4, 256, 0, stream>>>(buf1, dis, off, csr, buf0, N);
    gemm_resid_fc_kernel<<<ngemm, 256, 0, stream>>>(buf0, buf1, W2, b2, fcW, fcb, out, N);
  }
}

// Round 11
// 521.738 us; speedup vs baseline: 1.1741x; 1.1741x over previous
//
#include <hip/hip_runtime.h>
#include <hip/hip_bf16.h>
#include <stdint.h>

#define HID 128
#define NPART 8
#define NCHUNK 256
#define MCHUNK 4096   // edges per radixA block
#define LBITS 9       // local dst bits; bucket = dst>>LBITS (512 dsts/bucket)
#define SBITS 22      // src bits in packed word (N must be <= 1<<22)
#define NCH 8         // src chunks for locality ordering

// ---------------- mask storage detection ----------------
__global__ void detect_mask_kernel(const unsigned char* __restrict__ p, int nbytes,
                                   int nfloat, int* __restrict__ flags) {
  int stride = blockDim.x * gridDim.x;
  for (int i = blockIdx.x * blockDim.x + threadIdx.x; i < nbytes; i += stride) {
    if ((i & 3) && p[i] != 0) { atomicOr(&flags[0], 1); break; }
  }
  const float* fp = (const float*)p;
  for (int i = blockIdx.x * blockDim.x + threadIdx.x; i < nfloat; i += stride) {
    float f = fp[i];
    if (!(f == 0.0f || f == 1.0f)) { atomicOr(&flags[1], 1); break; }
  }
}

__global__ void expand_mask_h0(const void* __restrict__ maskp, const float4* __restrict__ x4,
                               const int* __restrict__ flags, const float* __restrict__ dis,
                               float* __restrict__ maskout, float* __restrict__ cvec,
                               float4* __restrict__ h0s, int N) {
  int i = blockIdx.x * blockDim.x + threadIdx.x;
  if (i >= N) return;
  float m;
  if (flags[0] == 0)      m = (((const int*)maskp)[i] != 0) ? 1.f : 0.f;
  else if (flags[1] == 0) m = (((const float*)maskp)[i] != 0.f) ? 1.f : 0.f;
  else                    m = (((const unsigned char*)maskp)[i] != 0) ? 1.f : 0.f;
  maskout[i] = m;
  float4 xv = x4[i];
  float4 h0 = make_float4(m * xv.x, m * xv.y, m * xv.z, m * xv.w);
  float* cv = cvec + (size_t)i * 8;
  cv[4] = h0.x; cv[5] = h0.y; cv[6] = h0.z; cv[7] = h0.w;
  float d = dis[i];
  h0s[i] = make_float4(d * h0.x, d * h0.y, d * h0.z, d * h0.w);
}

// ---------------- CSR build: two-pass LDS-staged radix ----------------
__global__ void init_gcur_kernel(int* __restrict__ gcur, int n, int CAPB) {
  int i = blockIdx.x * blockDim.x + threadIdx.x;
  if (i < n) gcur[i] = i * CAPB;
}

__global__ void radixA_kernel(const int* __restrict__ src, const int* __restrict__ dst,
                              int* __restrict__ gcur, uint32_t* __restrict__ bdata,
                              int nbin, int CAPB, int E) {
  __shared__ uint32_t sv[MCHUNK];
  __shared__ uint16_t sb[MCHUNK];
  __shared__ int bcnt[1024], boff[1024], gbase[1024];
  __shared__ int wsum[4];
  int t = threadIdx.x;
  int base = blockIdx.x * MCHUNK;
  int m = E - base; if (m > MCHUNK) m = MCHUNK;
  for (int i = t; i < 1024; i += 256) bcnt[i] = 0;
  __syncthreads();
  uint32_t pk[16]; short bn[16];
#pragma unroll
  for (int j = 0; j < 16; j++) {
    int i = base + t + j * 256;
    if (i < base + m) {
      int d = __builtin_nontemporal_load(&dst[i]);
      int s = __builtin_nontemporal_load(&src[i]);
      int b = d >> LBITS;
      pk[j] = ((uint32_t)(d & ((1 << LBITS) - 1)) << SBITS) | (uint32_t)s;
      bn[j] = (short)b;
      atomicAdd(&bcnt[b], 1);
    } else bn[j] = -1;
  }
  __syncthreads();
  {
    int lane = t & 63, w = t >> 6, i0 = t * 4;
    int v0 = bcnt[i0], v1 = bcnt[i0 + 1], v2 = bcnt[i0 + 2], v3 = bcnt[i0 + 3];
    int ts = v0 + v1 + v2 + v3, sc = ts;
    for (int d = 1; d < 64; d <<= 1) { int x = __shfl_up(sc, d, 64); if (lane >= d) sc += x; }
    if (lane == 63) wsum[w] = sc;
    __syncthreads();
    int wo = 0;
    for (int k = 0; k < w; k++) wo += wsum[k];
    int excl = wo + sc - ts;
    boff[i0] = excl; boff[i0 + 1] = excl + v0;
    boff[i0 + 2] = excl + v0 + v1; boff[i0 + 3] = excl + v0 + v1 + v2;
  }
  __syncthreads();
  for (int i = t; i < nbin; i += 256) {
    int c = bcnt[i];
    gbase[i] = c ? atomicAdd(&gcur[i], c) : 0;
  }
  __syncthreads();
  for (int i = t; i < nbin; i += 256) bcnt[i] = boff[i];
  __syncthreads();
#pragma unroll
  for (int j = 0; j < 16; j++) {
    if (bn[j] >= 0) {
      int p = atomicAdd(&bcnt[bn[j]], 1);
      sv[p] = pk[j];
      sb[p] = (uint16_t)bn[j];
    }
  }
  __syncthreads();
  for (int i = t; i < m; i += 256) {
    int b = sb[i];
    int gp = gbase[b] + (i - boff[b]);
    if (gp < (b + 1) * CAPB) bdata[gp] = sv[i];
  }
}

// fused btot + scan (single block, nbin <= 1024)
__global__ void bucket_meta_kernel(const int* __restrict__ gcur, int* __restrict__ bstart,
                                   int nbin, int CAPB) {
  __shared__ int wsum[4];
  int t = threadIdx.x, lane = t & 63, w = t >> 6, i0 = t * 4;
  int v[4];
#pragma unroll
  for (int q = 0; q < 4; q++) {
    int i = i0 + q;
    int c = 0;
    if (i < nbin) {
      c = gcur[i] - i * CAPB;
      if (c > CAPB) c = CAPB;
    }
    v[q] = c;
  }
  int ts = v[0] + v[1] + v[2] + v[3], sc = ts;
  for (int d = 1; d < 64; d <<= 1) { int x = __shfl_up(sc, d, 64); if (lane >= d) sc += x; }
  if (lane == 63) wsum[w] = sc;
  __syncthreads();
  int wo = 0;
  for (int k = 0; k < w; k++) wo += wsum[k];
  int excl = wo + sc - ts;
  int e[4] = {excl, excl + v[0], excl + v[0] + v[1], excl + v[0] + v[1] + v[2]};
#pragma unroll
  for (int q = 0; q < 4; q++)
    if (i0 + q < nbin) bstart[i0 + q] = e[q];
  if (t == 255) bstart[nbin] = wo + sc;
}

// Pass B: counting sort by key (local_dst<<3 | src_chunk) -> csr chunk-ordered per dst.
// Emits off[], dis[], rdis[]. LDS: 4096-bin cnt + loff (32KB).
__global__ void radixB_kernel(const uint32_t* __restrict__ bdata, const int* __restrict__ gcur,
                              const int* __restrict__ bstart, int CAPB,
                              int* __restrict__ off, float* __restrict__ dis,
                              float* __restrict__ rdis, int* __restrict__ csr,
                              int N, int E, int cshift) {
  __shared__ int cnt[4096], loff[4096];
  __shared__ int wsum[4];
  int b = blockIdx.x, t = threadIdx.x;
  int cb = gcur[b] - b * CAPB; if (cb > CAPB) cb = CAPB;
  int gb = bstart[b];
  const uint32_t* bd = bdata + (size_t)b * CAPB;
  for (int i = t; i < 4096; i += 256) cnt[i] = 0;
  __syncthreads();
  const uint32_t smask = (1u << SBITS) - 1;
  for (int i = t; i < cb; i += 256) {
    uint32_t v = bd[i];
    int ld = v >> SBITS;
    int src = (int)(v & smask);
    atomicAdd(&cnt[(ld << 3) | (src >> cshift)], 1);
  }
  __syncthreads();
  // scan 4096 bins: thread t owns bins [16t, 16t+16) = dsts 2t, 2t+1
  int lane = t & 63, w = t >> 6;
  int loc[16];
  int s = 0;
  int base16 = t * 16;
#pragma unroll
  for (int q = 0; q < 16; q++) { loc[q] = cnt[base16 + q]; s += loc[q]; }
  int sc = s;
  for (int d = 1; d < 64; d <<= 1) { int x = __shfl_up(sc, d, 64); if (lane >= d) sc += x; }
  if (lane == 63) wsum[w] = sc;
  __syncthreads();
  int wo = 0;
  for (int k = 0; k < w; k++) wo += wsum[k];
  int excl = wo + sc - s;
  {
    int run = excl;
#pragma unroll
    for (int q = 0; q < 16; q++) { loff[base16 + q] = run; run += loc[q]; }
  }
  // per-dst outputs
  int c0 = loc[0] + loc[1] + loc[2] + loc[3] + loc[4] + loc[5] + loc[6] + loc[7];
  int c1 = loc[8] + loc[9] + loc[10] + loc[11] + loc[12] + loc[13] + loc[14] + loc[15];
  int dst0 = b * (1 << LBITS) + 2 * t;
  if (dst0 < N) {
    off[dst0] = gb + excl;
    dis[dst0] = rsqrtf((float)c0 + 1.0f);
    rdis[dst0] = sqrtf((float)c0 + 1.0f);
  }
  if (dst0 + 1 < N) {
    off[dst0 + 1] = gb + excl + c0;
    dis[dst0 + 1] = rsqrtf((float)c1 + 1.0f);
    rdis[dst0 + 1] = sqrtf((float)c1 + 1.0f);
  }
  if (b == 0 && t == 0) off[N] = E;
  __syncthreads();
  for (int i = t; i < 4096; i += 256) cnt[i] = loff[i];
  __syncthreads();
  for (int i = t; i < cb; i += 256) {
    uint32_t v = bd[i];
    int ld = v >> SBITS;
    int src = (int)(v & smask);
    int p = atomicAdd(&cnt[(ld << 3) | (src >> cshift)], 1);
    csr[gb + p] = src;
  }
}

// ---------------- scan machinery (fallback path) ----------------
__global__ void scan1_kernel(const int* __restrict__ cnt, int* __restrict__ off,
                             int* __restrict__ bsum, float* __restrict__ dis, int N) {
  __shared__ int wsum[4];
  int t = threadIdx.x, lane = t & 63, w = t >> 6;
  int base = blockIdx.x * 1024 + t * 4;
  int v0 = (base + 0 < N) ? cnt[base + 0] : 0;
  int v1 = (base + 1 < N) ? cnt[base + 1] : 0;
  int v2 = (base + 2 < N) ? cnt[base + 2] : 0;
  int v3 = (base + 3 < N) ? cnt[base + 3] : 0;
  if (dis) {
    if (base + 0 < N) dis[base + 0] = rsqrtf((float)v0 + 1.0f);
    if (base + 1 < N) dis[base + 1] = rsqrtf((float)v1 + 1.0f);
    if (base + 2 < N) dis[base + 2] = rsqrtf((float)v2 + 1.0f);
    if (base + 3 < N) dis[base + 3] = rsqrtf((float)v3 + 1.0f);
  }
  int ts = v0 + v1 + v2 + v3;
  int sc = ts;
  for (int d = 1; d < 64; d <<= 1) {
    int x = __shfl_up(sc, d, 64);
    if (lane >= d) sc += x;
  }
  if (lane == 63) wsum[w] = sc;
  __syncthreads();
  int wo = 0;
  for (int i = 0; i < w; i++) wo += wsum[i];
  int excl = wo + sc - ts;
  if (base + 0 < N) off[base + 0] = excl;
  if (base + 1 < N) off[base + 1] = excl + v0;
  if (base + 2 < N) off[base + 2] = excl + v0 + v1;
  if (base + 3 < N) off[base + 3] = excl + v0 + v1 + v2;
  if (t == 255) bsum[blockIdx.x] = wo + sc;
}

__global__ void scan2_kernel(int* __restrict__ bsum, int nb) {
  if (threadIdx.x == 0 && blockIdx.x == 0) {
    int run = 0;
    for (int i = 0; i < nb; i++) { int v = bsum[i]; bsum[i] = run; run += v; }
  }
}

__global__ void scan3_kernel(int* __restrict__ off, const int* __restrict__ bsum,
                             int* __restrict__ cur, int N, int E) {
  int i = blockIdx.x * blockDim.x + threadIdx.x;
  if (i < N) {
    int o = off[i] + bsum[i >> 10];
    off[i] = o;
    if (cur) cur[i] = o;
  }
  if (i == 0) off[N] = E;
}

__global__ void hist_part_kernel(const int* __restrict__ dst, int* __restrict__ cnt,
                                 int E, int N) {
  int p = blockIdx.x & (NPART - 1);
  int chunk = blockIdx.x >> 3;
  int lo = (int)((long long)p * N / NPART);
  int hi = (int)((long long)(p + 1) * N / NPART);
  int stride = NCHUNK * 256;
  for (int e = chunk * 256 + threadIdx.x; e < E; e += stride) {
    int d = __builtin_nontemporal_load(&dst[e]);
    if (d >= lo && d < hi) atomicAdd(&cnt[d], 1);
  }
}

__global__ void fill_part_kernel(const int* __restrict__ src, const int* __restrict__ dst,
                                 int* __restrict__ cur, int* __restrict__ csr, int E, int N) {
  int p = blockIdx.x & (NPART - 1);
  int chunk = blockIdx.x >> 3;
  int lo = (int)((long long)p * N / NPART);
  int hi = (int)((long long)(p + 1) * N / NPART);
  int stride = NCHUNK * 256;
  for (int e = chunk * 256 + threadIdx.x; e < E; e += stride) {
    int d = __builtin_nontemporal_load(&dst[e]);
    if (d >= lo && d < hi) {
      int s = __builtin_nontemporal_load(&src[e]);
      int pos = atomicAdd(&cur[d], 1);
      csr[pos] = s;
    }
  }
}

// ---------------- layer 0 aggregation ----------------
__global__ void l0_agg_kernel(const float4* __restrict__ h0s, const float* __restrict__ dis,
                              const int* __restrict__ off, const int* __restrict__ csr,
                              float* __restrict__ cvec, int N) {
  int n = blockIdx.x * blockDim.x + threadIdx.x;
  if (n >= N) return;
  float4 a = h0s[n];
  int e0 = off[n], e1 = off[n + 1];
  int i = e0;
  for (; i < e1 && (i & 3); i++) {
    float4 v = h0s[csr[i]];
    a.x += v.x; a.y += v.y; a.z += v.z; a.w += v.w;
  }
  for (; i + 4 <= e1; i += 4) {
    int4 c = *(const int4*)&csr[i];
    float4 v0 = h0s[c.x], v1 = h0s[c.y], v2 = h0s[c.z], v3 = h0s[c.w];
    a.x += v0.x + v1.x + v2.x + v3.x;
    a.y += v0.y + v1.y + v2.y + v3.y;
    a.z += v0.z + v1.z + v2.z + v3.z;
    a.w += v0.w + v1.w + v2.w + v3.w;
  }
  for (; i < e1; i++) {
    float4 v = h0s[csr[i]];
    a.x += v.x; a.y += v.y; a.z += v.z; a.w += v.w;
  }
  float dn = dis[n];
  float* cv = cvec + (size_t)n * 8;
  cv[0] = dn * a.x; cv[1] = dn * a.y; cv[2] = dn * a.z; cv[3] = dn * a.w;
}

// h1 = relu(...); writes hb (bf16 dis*h1) and optionally f32 h1 (fallback)
__global__ void l0_combine_kernel(const float* __restrict__ cvec, const float* __restrict__ W0,
                                  const float* __restrict__ b0, const float* __restrict__ resW,
                                  const float* __restrict__ resb, const float* __restrict__ dis,
                                  float* __restrict__ h1, __hip_bfloat16* __restrict__ hbout) {
  int idx = blockIdx.x * blockDim.x + threadIdx.x;
  int n = idx >> 7, c = idx & 127;
  const float* cv = cvec + (size_t)n * 8;
  float acc = b0[c] + resb[c];
#pragma unroll
  for (int k = 0; k < 4; k++) {
    acc += cv[k] * W0[k * HID + c];
    acc += cv[4 + k] * resW[k * HID + c];
  }
  float v = fmaxf(acc, 0.0f);
  if (h1) h1[idx] = v;
  if (hbout) hbout[idx] = __float2bfloat16(dis[n] * v);
}

// ---------------- 128-dim aggregation: bf16 gather -> f32 out, int4 csr loads ----------------
#define ACC1(W) { a0 += __uint_as_float((W) << 16); a1 += __uint_as_float((W) & 0xffff0000u); }
__global__ void agg_hid_bf16_kernel(const uint32_t* __restrict__ hb, const float* __restrict__ dis,
                                    const int* __restrict__ off, const int* __restrict__ csr,
                                    float* __restrict__ out, int N) {
  int node = blockIdx.x * 4 + (threadIdx.x >> 6);
  int lane = threadIdx.x & 63;
  if (node >= N) return;
  uint32_t w = hb[(size_t)node * 64 + lane];
  float a0 = __uint_as_float(w << 16);
  float a1 = __uint_as_float(w & 0xffff0000u);
  int e0 = off[node], e1 = off[node + 1];
  int i = e0;
  for (; i < e1 && (i & 3); i++) {
    uint32_t ww = hb[(size_t)csr[i] * 64 + lane];
    ACC1(ww)
  }
  for (; i + 8 <= e1; i += 8) {
    int4 c0 = *(const int4*)&csr[i];
    int4 c1 = *(const int4*)&csr[i + 4];
    uint32_t w0 = hb[(size_t)c0.x * 64 + lane];
    uint32_t w1 = hb[(size_t)c0.y * 64 + lane];
    uint32_t w2 = hb[(size_t)c0.z * 64 + lane];
    uint32_t w3 = hb[(size_t)c0.w * 64 + lane];
    uint32_t w4 = hb[(size_t)c1.x * 64 + lane];
    uint32_t w5 = hb[(size_t)c1.y * 64 + lane];
    uint32_t w6 = hb[(size_t)c1.z * 64 + lane];
    uint32_t w7 = hb[(size_t)c1.w * 64 + lane];
    ACC1(w0) ACC1(w1) ACC1(w2) ACC1(w3) ACC1(w4) ACC1(w5) ACC1(w6) ACC1(w7)
  }
  for (; i + 4 <= e1; i += 4) {
    int4 c = *(const int4*)&csr[i];
    uint32_t w0 = hb[(size_t)c.x * 64 + lane];
    uint32_t w1 = hb[(size_t)c.y * 64 + lane];
    uint32_t w2 = hb[(size_t)c.z * 64 + lane];
    uint32_t w3 = hb[(size_t)c.w * 64 + lane];
    ACC1(w0) ACC1(w1) ACC1(w2) ACC1(w3)
  }
  for (; i < e1; i++) {
    uint32_t ww = hb[(size_t)csr[i] * 64 + lane];
    ACC1(ww)
  }
  float dn = dis[node];
  *(float2*)&out[(size_t)node * HID + 2 * lane] = make_float2(dn * a0, dn * a1);
}

// f32 fallback aggregation
__global__ void agg_hid_kernel(const float* __restrict__ h, const float* __restrict__ dis,
                               const int* __restrict__ off, const int* __restrict__ csr,
                               float* __restrict__ out, int N) {
  int node = blockIdx.x * 4 + (threadIdx.x >> 6);
  int lane = threadIdx.x & 63;
  if (node >= N) return;
  float dn = dis[node];
  const float* hrow = h + (size_t)node * HID;
  float a0 = dn * hrow[lane];
  float a1 = dn * hrow[lane + 64];
  int e0 = off[node], e1 = off[node + 1];
  for (int i = e0; i < e1; i++) {
    int s = csr[i];
    float d = dis[s];
    const float* hs = h + (size_t)s * HID;
    a0 += d * hs[lane];
    a1 += d * hs[lane + 64];
  }
  out[(size_t)node * HID + lane] = dn * a0;
  out[(size_t)node * HID + lane + 64] = dn * a1;
}

// ---------------- h_next = relu(ag @ W + b + hb_res*rdis); emit bf16 only ----------------
__global__ void gemm_resid_relu_kernel(const float* __restrict__ ag,
                                       const __hip_bfloat16* __restrict__ hbres,
                                       const float* __restrict__ rdis,
                                       const float* __restrict__ W, const float* __restrict__ b,
                                       const float* __restrict__ dis,
                                       __hip_bfloat16* __restrict__ hbout, int N) {
  __shared__ float ash[64 * HID];
  int t = threadIdx.x;
  int n0 = blockIdx.x * 64;
  for (int i = t; i < 64 * HID; i += 256) {
    int gn = n0 + (i >> 7);
    ash[i] = (gn < N) ? ag[(size_t)gn * HID + (i & 127)] : 0.0f;
  }
  __syncthreads();
  int tc = t & 31;
  int tn = t >> 5;
  float acc[8][4];
#pragma unroll
  for (int j = 0; j < 8; j++)
#pragma unroll
    for (int q = 0; q < 4; q++) acc[j][q] = 0.0f;

  for (int k = 0; k < HID; k += 4) {
    float4 w0 = *(const float4*)&W[(k + 0) * HID + tc * 4];
    float4 w1 = *(const float4*)&W[(k + 1) * HID + tc * 4];
    float4 w2 = *(const float4*)&W[(k + 2) * HID + tc * 4];
    float4 w3 = *(const float4*)&W[(k + 3) * HID + tc * 4];
#pragma unroll
    for (int j = 0; j < 8; j++) {
      float4 a = *(const float4*)&ash[(tn * 8 + j) * HID + k];
      acc[j][0] += a.x * w0.x + a.y * w1.x + a.z * w2.x + a.w * w3.x;
      acc[j][1] += a.x * w0.y + a.y * w1.y + a.z * w2.y + a.w * w3.y;
      acc[j][2] += a.x * w0.z + a.y * w1.z + a.z * w2.z + a.w * w3.z;
      acc[j][3] += a.x * w0.w + a.y * w1.w + a.z * w2.w + a.w * w3.w;
    }
  }
  float4 bv = *(const float4*)&b[tc * 4];
#pragma unroll
  for (int j = 0; j < 8; j++) {
    int gn = n0 + tn * 8 + j;
    if (gn < N) {
      float rd = rdis[gn];
      uint2 hu = *(const uint2*)&hbres[(size_t)gn * HID + tc * 4];
      float h0v = __uint_as_float(hu.x << 16) * rd;
      float h1v = __uint_as_float(hu.x & 0xffff0000u) * rd;
      float h2v = __uint_as_float(hu.y << 16) * rd;
      float h3v = __uint_as_float(hu.y & 0xffff0000u) * rd;
      float4 o;
      o.x = fmaxf(acc[j][0] + bv.x + h0v, 0.0f);
      o.y = fmaxf(acc[j][1] + bv.y + h1v, 0.0f);
      o.z = fmaxf(acc[j][2] + bv.z + h2v, 0.0f);
      o.w = fmaxf(acc[j][3] + bv.w + h3v, 0.0f);
      float dnn = dis[gn];
      __hip_bfloat162 p01 = __float22bfloat162_rn(make_float2(dnn * o.x, dnn * o.y));
      __hip_bfloat162 p23 = __float22bfloat162_rn(make_float2(dnn * o.z, dnn * o.w));
      *(__hip_bfloat162*)&hbout[(size_t)gn * HID + tc * 4] = p01;
      *(__hip_bfloat162*)&hbout[(size_t)gn * HID + tc * 4 + 2] = p23;
    }
  }
}

// ---------------- layer 2 fused: h3 = relu(ag@W + b + hb_res*rdis); out = h3@fcW + fcb ----------------
__global__ void gemm_resid_fc_kernel(const float* __restrict__ ag,
                                     const __hip_bfloat16* __restrict__ hbres,
                                     const float* __restrict__ rdis,
                                     const float* __restrict__ W, const float* __restrict__ b,
                                     const float* __restrict__ fcW, const float* __restrict__ fcb,
                                     float* __restrict__ out, int N) {
  __shared__ float ash[64 * HID];
  int t = threadIdx.x;
  int n0 = blockIdx.x * 64;
  for (int i = t; i < 64 * HID; i += 256) {
    int gn = n0 + (i >> 7);
    ash[i] = (gn < N) ? ag[(size_t)gn * HID + (i & 127)] : 0.0f;
  }
  __syncthreads();
  int tc = t & 31;
  int tn = t >> 5;
  float acc[8][4];
#pragma unroll
  for (int j = 0; j < 8; j++)
#pragma unroll
    for (int q = 0; q < 4; q++) acc[j][q] = 0.0f;

  for (int k = 0; k < HID; k += 4) {
    float4 w0 = *(const float4*)&W[(k + 0) * HID + tc * 4];
    float4 w1 = *(const float4*)&W[(k + 1) * HID + tc * 4];
    float4 w2 = *(const float4*)&W[(k + 2) * HID + tc * 4];
    float4 w3 = *(const float4*)&W[(k + 3) * HID + tc * 4];
#pragma unroll
    for (int j = 0; j < 8; j++) {
      float4 a = *(const float4*)&ash[(tn * 8 + j) * HID + k];
      acc[j][0] += a.x * w0.x + a.y * w1.x + a.z * w2.x + a.w * w3.x;
      acc[j][1] += a.x * w0.y + a.y * w1.y + a.z * w2.y + a.w * w3.y;
      acc[j][2] += a.x * w0.z + a.y * w1.z + a.z * w2.z + a.w * w3.z;
      acc[j][3] += a.x * w0.w + a.y * w1.w + a.z * w2.w + a.w * w3.w;
    }
  }
  float4 f0 = *(const float4*)&fcW[(tc * 4 + 0) * 4];
  float4 f1 = *(const float4*)&fcW[(tc * 4 + 1) * 4];
  float4 f2 = *(const float4*)&fcW[(tc * 4 + 2) * 4];
  float4 f3 = *(const float4*)&fcW[(tc * 4 + 3) * 4];
  float4 bv = *(const float4*)&b[tc * 4];
  float4 fb = *(const float4*)&fcb[0];
#pragma unroll
  for (int j = 0; j < 8; j++) {
    int gn = n0 + tn * 8 + j;
    float4 o = make_float4(0.f, 0.f, 0.f, 0.f);
    if (gn < N) {
      float rd = rdis[gn];
      uint2 hu = *(const uint2*)&hbres[(size_t)gn * HID + tc * 4];
      o.x = fmaxf(acc[j][0] + bv.x + __uint_as_float(hu.x << 16) * rd, 0.0f);
      o.y = fmaxf(acc[j][1] + bv.y + __uint_as_float(hu.x & 0xffff0000u) * rd, 0.0f);
      o.z = fmaxf(acc[j][2] + bv.z + __uint_as_float(hu.y << 16) * rd, 0.0f);
      o.w = fmaxf(acc[j][3] + bv.w + __uint_as_float(hu.y & 0xffff0000u) * rd, 0.0f);
    }
    float r0 = o.x * f0.x + o.y * f1.x + o.z * f2.x + o.w * f3.x;
    float r1 = o.x * f0.y + o.y * f1.y + o.z * f2.y + o.w * f3.y;
    float r2 = o.x * f0.z + o.y * f1.z + o.z * f2.z + o.w * f3.z;
    float r3 = o.x * f0.w + o.y * f1.w + o.z * f2.w + o.w * f3.w;
#pragma unroll
    for (int d = 1; d < 32; d <<= 1) {
      r0 += __shfl_xor(r0, d, 64);
      r1 += __shfl_xor(r1, d, 64);
      r2 += __shfl_xor(r2, d, 64);
      r3 += __shfl_xor(r3, d, 64);
    }
    if (tc == 0 && gn < N)
      *(float4*)&out[(size_t)gn * 4] =
          make_float4(r0 + fb.x, r1 + fb.y, r2 + fb.z, r3 + fb.w);
  }
}

// ---------------- f32 fallback gemm kernels ----------------
__global__ void gemm_resid_relu_f32_kernel(const float* __restrict__ ag, float* __restrict__ hout,
                                           const float* __restrict__ hres,
                                           const float* __restrict__ W, const float* __restrict__ b,
                                           int N) {
  __shared__ float ash[64 * HID];
  int t = threadIdx.x;
  int n0 = blockIdx.x * 64;
  for (int i = t; i < 64 * HID; i += 256) {
    int gn = n0 + (i >> 7);
    ash[i] = (gn < N) ? ag[(size_t)gn * HID + (i & 127)] : 0.0f;
  }
  __syncthreads();
  int tc = t & 31;
  int tn = t >> 5;
  float acc[8][4];
#pragma unroll
  for (int j = 0; j < 8; j++)
#pragma unroll
    for (int q = 0; q < 4; q++) acc[j][q] = 0.0f;
  for (int k = 0; k < HID; k += 4) {
    float4 w0 = *(const float4*)&W[(k + 0) * HID + tc * 4];
    float4 w1 = *(const float4*)&W[(k + 1) * HID + tc * 4];
    float4 w2 = *(const float4*)&W[(k + 2) * HID + tc * 4];
    float4 w3 = *(const float4*)&W[(k + 3) * HID + tc * 4];
#pragma unroll
    for (int j = 0; j < 8; j++) {
      float4 a = *(const float4*)&ash[(tn * 8 + j) * HID + k];
      acc[j][0] += a.x * w0.x + a.y * w1.x + a.z * w2.x + a.w * w3.x;
      acc[j][1] += a.x * w0.y + a.y * w1.y + a.z * w2.y + a.w * w3.y;
      acc[j][2] += a.x * w0.z + a.y * w1.z + a.z * w2.z + a.w * w3.z;
      acc[j][3] += a.x * w0.w + a.y * w1.w + a.z * w2.w + a.w * w3.w;
    }
  }
  float4 bv = *(const float4*)&b[tc * 4];
#pragma unroll
  for (int j = 0; j < 8; j++) {
    int gn = n0 + tn * 8 + j;
    if (gn < N) {
      float4 hv = *(const float4*)&hres[(size_t)gn * HID + tc * 4];
      float4 o;
      o.x = fmaxf(acc[j][0] + bv.x + hv.x, 0.0f);
      o.y = fmaxf(acc[j][1] + bv.y + hv.y, 0.0f);
      o.z = fmaxf(acc[j][2] + bv.z + hv.z, 0.0f);
      o.w = fmaxf(acc[j][3] + bv.w + hv.w, 0.0f);
      *(float4*)&hout[(size_t)gn * HID + tc * 4] = o;
    }
  }
}

__global__ void gemm_resid_fc_f32_kernel(const float* __restrict__ ag,
                                         const float* __restrict__ hres,
                                         const float* __restrict__ W, const float* __restrict__ b,
                                         const float* __restrict__ fcW, const float* __restrict__ fcb,
                                         float* __restrict__ out, int N) {
  __shared__ float ash[64 * HID];
  int t = threadIdx.x;
  int n0 = blockIdx.x * 64;
  for (int i = t; i < 64 * HID; i += 256) {
    int gn = n0 + (i >> 7);
    ash[i] = (gn < N) ? ag[(size_t)gn * HID + (i & 127)] : 0.0f;
  }
  __syncthreads();
  int tc = t & 31;
  int tn = t >> 5;
  float acc[8][4];
#pragma unroll
  for (int j = 0; j < 8; j++)
#pragma unroll
    for (int q = 0; q < 4; q++) acc[j][q] = 0.0f;
  for (int k = 0; k < HID; k += 4) {
    float4 w0 = *(const float4*)&W[(k + 0) * HID + tc * 4];
    float4 w1 = *(const float4*)&W[(k + 1) * HID + tc * 4];
    float4 w2 = *(const float4*)&W[(k + 2) * HID + tc * 4];
    float4 w3 = *(const float4*)&W[(k + 3) * HID + tc * 4];
#pragma unroll
    for (int j = 0; j < 8; j++) {
      float4 a = *(const float4*)&ash[(tn * 8 + j) * HID + k];
      acc[j][0] += a.x * w0.x + a.y * w1.x + a.z * w2.x + a.w * w3.x;
      acc[j][1] += a.x * w0.y + a.y * w1.y + a.z * w2.y + a.w * w3.y;
      acc[j][2] += a.x * w0.z + a.y * w1.z + a.z * w2.z + a.w * w3.z;
      acc[j][3] += a.x * w0.w + a.y * w1.w + a.z * w2.w + a.w * w3.w;
    }
  }
  float4 f0 = *(const float4*)&fcW[(tc * 4 + 0) * 4];
  float4 f1 = *(const float4*)&fcW[(tc * 4 + 1) * 4];
  float4 f2 = *(const float4*)&fcW[(tc * 4 + 2) * 4];
  float4 f3 = *(const float4*)&fcW[(tc * 4 + 3) * 4];
  float4 bv = *(const float4*)&b[tc * 4];
  float4 fb = *(const float4*)&fcb[0];
#pragma unroll
  for (int j = 0; j < 8; j++) {
    int gn = n0 + tn * 8 + j;
    float4 o = make_float4(0.f, 0.f, 0.f, 0.f);
    if (gn < N) {
      float4 hv = *(const float4*)&hres[(size_t)gn * HID + tc * 4];
      o.x = fmaxf(acc[j][0] + bv.x + hv.x, 0.0f);
      o.y = fmaxf(acc[j][1] + bv.y + hv.y, 0.0f);
      o.z = fmaxf(acc[j][2] + bv.z + hv.z, 0.0f);
      o.w = fmaxf(acc[j][3] + bv.w + hv.w, 0.0f);
    }
    float r0 = o.x * f0.x + o.y * f1.x + o.z * f2.x + o.w * f3.x;
    float r1 = o.x * f0.y + o.y * f1.y + o.z * f2.y + o.w * f3.y;
    float r2 = o.x * f0.z + o.y * f1.z + o.z * f2.z + o.w * f3.z;
    float r3 = o.x * f0.w + o.y * f1.w + o.z * f2.w + o.w * f3.w;
#pragma unroll
    for (int d = 1; d < 32; d <<= 1) {
      r0 += __shfl_xor(r0, d, 64);
      r1 += __shfl_xor(r1, d, 64);
      r2 += __shfl_xor(r2, d, 64);
      r3 += __shfl_xor(r3, d, 64);
    }
    if (tc == 0 && gn < N)
      *(float4*)&out[(size_t)gn * 4] =
          make_float4(r0 + fb.x, r1 + fb.y, r2 + fb.z, r3 + fb.w);
  }
}

// ---------------- host ----------------
extern "C" void kernel_launch(void* const* d_in, const int* in_sizes, int n_in,
                              void* d_out, int out_size, void* d_ws, size_t ws_size,
                              hipStream_t stream) {
  const float* x = (const float*)d_in[0];
  const int* edge = (const int*)d_in[1];
  const void* maskp = d_in[2];
  const float* W0 = (const float*)d_in[3];
  const float* b0 = (const float*)d_in[4];
  const float* resW = (const float*)d_in[5];
  const float* resb = (const float*)d_in[6];
  const float* W1 = (const float*)d_in[7];
  const float* b1 = (const float*)d_in[8];
  const float* W2 = (const float*)d_in[9];
  const float* b2 = (const float*)d_in[10];
  const float* fcW = (const float*)d_in[11];
  const float* fcb = (const float*)d_in[12];
  float* out = (float*)d_out;

  int N = in_sizes[0] / 4;
  int E = in_sizes[1] / 2;
  const int* srcp = edge;
  const int* dstp = edge + E;

  char* ws = (char*)d_ws;
  size_t cursor = 0;
  auto alloc = [&](size_t bytes) { char* p = ws + cursor; cursor += (bytes + 511) & ~(size_t)511; return p; };
  int* flags = (int*)alloc(16);
  int* cnt = (int*)alloc((size_t)N * 4);   // fallback path only
  float* dis = (float*)alloc((size_t)N * 4);
  float* rdis = (float*)alloc((size_t)N * 4);
  int* off = (int*)alloc((size_t)(N + 1) * 4);
  int* bsum = (int*)alloc(1024);
  int nbin = (N + (1 << LBITS) - 1) >> LBITS;
  int* gcur = (int*)alloc((size_t)(nbin + 1) * 4);
  int* bstart = (int*)alloc((size_t)(nbin + 1) * 4);
  int* csr = (int*)alloc((size_t)E * 4);
  float* h0s = (float*)alloc((size_t)N * 4 * 4);
  float* cvec = (float*)alloc((size_t)N * 8 * 4);
  float* buf0 = (float*)alloc((size_t)N * HID * 4);  // agg output (f32) / fallback h
  float* buf1 = (float*)alloc((size_t)N * HID * 4);  // bdata alias / fallback h
  size_t base_cursor = cursor;
  __hip_bfloat16* hb1 = (__hip_bfloat16*)alloc((size_t)N * HID * 2);
  __hip_bfloat16* hb2 = (__hip_bfloat16*)alloc((size_t)N * HID * 2);
  bool use_bf16 = (cursor <= ws_size);
  if (!use_bf16) {
    hb1 = nullptr; hb2 = nullptr;
    if (base_cursor > ws_size) return;
  }

  long long expect = (long long)E / (nbin > 0 ? nbin : 1);
  int CAPB = (int)((((expect * 5) / 4 + 127) / 64) * 64);
  if (CAPB < 256) CAPB = 256;
  size_t bdata_bytes = (size_t)nbin * CAPB * 4;
  bool use_radix = (N <= (1 << SBITS)) && (nbin <= 1024) &&
                   (bdata_bytes <= (size_t)N * HID * 4);
  uint32_t* bdata = (uint32_t*)buf1;

  // src chunk shift: smallest shift with (N-1)>>shift <= 7
  int cshift = 0;
  while (((N - 1) >> cshift) > (NCH - 1)) cshift++;

  int nThreadsN = (N + 255) / 256;
  int ngemm = (N + 63) / 64;

  hipMemsetAsync(flags, 0, 16, stream);
  detect_mask_kernel<<<256, 256, 0, stream>>>((const unsigned char*)maskp, N, N / 4, flags);

  if (use_radix) {
    init_gcur_kernel<<<(nbin + 255) / 256, 256, 0, stream>>>(gcur, nbin, CAPB);
    radixA_kernel<<<(E + MCHUNK - 1) / MCHUNK, 256, 0, stream>>>(srcp, dstp, gcur, bdata,
                                                                 nbin, CAPB, E);
    bucket_meta_kernel<<<1, 256, 0, stream>>>(gcur, bstart, nbin, CAPB);
    radixB_kernel<<<nbin, 256, 0, stream>>>(bdata, gcur, bstart, CAPB, off, dis, rdis,
                                            csr, N, E, cshift);
  } else {
    hipMemsetAsync(cnt, 0, (size_t)N * 4, stream);
    int nb = (N + 1023) / 1024;
    hist_part_kernel<<<NPART * NCHUNK, 256, 0, stream>>>(dstp, cnt, E, N);
    scan1_kernel<<<nb, 256, 0, stream>>>(cnt, off, bsum, dis, N);
    scan2_kernel<<<1, 64, 0, stream>>>(bsum, nb);
    scan3_kernel<<<nThreadsN, 256, 0, stream>>>(off, bsum, cnt, N, E);
    fill_part_kernel<<<NPART * NCHUNK, 256, 0, stream>>>(srcp, dstp, cnt, csr, E, N);
  }

  expand_mask_h0<<<nThreadsN, 256, 0, stream>>>(maskp, (const float4*)x, flags, dis,
                                                out + (size_t)N * 4, cvec, (float4*)h0s, N);

  // layer 0
  l0_agg_kernel<<<nThreadsN, 256, 0, stream>>>((const float4*)h0s, dis, off, csr, cvec, N);

  if (use_bf16) {
    l0_combine_kernel<<<(N * HID + 255) / 256, 256, 0, stream>>>(cvec, W0, b0, resW, resb, dis,
                                                                 nullptr, hb1);
    // layer 1: agg(hb1) -> buf0 (f32) ; h2 via gemm -> hb2 (bf16 only)
    agg_hid_bf16_kernel<<<(N + 3) / 4, 256, 0, stream>>>((const uint32_t*)hb1, dis, off, csr,
                                                         buf0, N);
    gemm_resid_relu_kernel<<<ngemm, 256, 0, stream>>>(buf0, hb1, rdis, W1, b1, dis, hb2, N);
    // layer 2: agg(hb2) -> buf0 ; fused gemm+res+relu+fc -> out
    agg_hid_bf16_kernel<<<(N + 3) / 4, 256, 0, stream>>>((const uint32_t*)hb2, dis, off, csr,
                                                         buf0, N);
    gemm_resid_fc_kernel<<<ngemm, 256, 0, stream>>>(buf0, hb2, rdis, W2, b2, fcW, fcb, out, N);
  } else {
    l0_combine_kernel<<<(N * HID + 255) / 256, 256, 0, stream>>>(cvec, W0, b0, resW, resb, dis,
                                                                 buf0, nullptr);
    agg_hid_kernel<<<(N + 3) / 4, 256, 0, stream>>>(buf0, dis, off, csr, buf1, N);
    gemm_resid_relu_f32_kernel<<<ngemm, 256, 0, stream>>>(buf1, buf1, buf0, W1, b1, N);
    agg_hid_kernel<<<(N + 3) / 4, 256, 0, stream>>>(buf1, dis, off, csr, buf0, N);
    gemm_resid_fc_f32_kernel<<<ngemm, 256, 0, stream>>>(buf0, buf1, W2, b2, fcW, fcb, out, N);
  }
}

// Round 12
// 510.556 us; speedup vs baseline: 1.1998x; 1.0219x over previous
//
#include <hip/hip_runtime.h>
#include <hip/hip_bf16.h>
#include <stdint.h>

#define HID 128
#define NPART 8
#define NCHUNK 256
#define MCHUNK 4096   // edges per radixA block
#define LBITS 9       // local dst bits; bucket = dst>>LBITS (512 dsts/bucket)
#define SBITS 22      // src bits in packed word (N must be <= 1<<22)
#define NCH 8         // src chunks for locality ordering

typedef float f2 __attribute__((ext_vector_type(2)));

// ---------------- mask storage detection ----------------
__global__ void detect_mask_kernel(const unsigned char* __restrict__ p, int nbytes,
                                   int nfloat, int* __restrict__ flags) {
  int stride = blockDim.x * gridDim.x;
  for (int i = blockIdx.x * blockDim.x + threadIdx.x; i < nbytes; i += stride) {
    if ((i & 3) && p[i] != 0) { atomicOr(&flags[0], 1); break; }
  }
  const float* fp = (const float*)p;
  for (int i = blockIdx.x * blockDim.x + threadIdx.x; i < nfloat; i += stride) {
    float f = fp[i];
    if (!(f == 0.0f || f == 1.0f)) { atomicOr(&flags[1], 1); break; }
  }
}

__global__ void expand_mask_h0(const void* __restrict__ maskp, const float4* __restrict__ x4,
                               const int* __restrict__ flags, const float* __restrict__ dis,
                               float* __restrict__ maskout, float* __restrict__ cvec,
                               float4* __restrict__ h0s, int N) {
  int i = blockIdx.x * blockDim.x + threadIdx.x;
  if (i >= N) return;
  float m;
  if (flags[0] == 0)      m = (((const int*)maskp)[i] != 0) ? 1.f : 0.f;
  else if (flags[1] == 0) m = (((const float*)maskp)[i] != 0.f) ? 1.f : 0.f;
  else                    m = (((const unsigned char*)maskp)[i] != 0) ? 1.f : 0.f;
  maskout[i] = m;
  float4 xv = x4[i];
  float4 h0 = make_float4(m * xv.x, m * xv.y, m * xv.z, m * xv.w);
  float* cv = cvec + (size_t)i * 8;
  cv[4] = h0.x; cv[5] = h0.y; cv[6] = h0.z; cv[7] = h0.w;
  float d = dis[i];
  h0s[i] = make_float4(d * h0.x, d * h0.y, d * h0.z, d * h0.w);
}

// ---------------- CSR build: two-pass LDS-staged radix ----------------
__global__ void init_gcur_kernel(int* __restrict__ gcur, int n, int CAPB) {
  int i = blockIdx.x * blockDim.x + threadIdx.x;
  if (i < n) gcur[i] = i * CAPB;
}

__global__ void radixA_kernel(const int* __restrict__ src, const int* __restrict__ dst,
                              int* __restrict__ gcur, uint32_t* __restrict__ bdata,
                              int nbin, int CAPB, int E) {
  __shared__ uint32_t sv[MCHUNK];
  __shared__ uint16_t sb[MCHUNK];
  __shared__ int bcnt[1024], boff[1024], gbase[1024];
  __shared__ int wsum[4];
  int t = threadIdx.x;
  int base = blockIdx.x * MCHUNK;
  int m = E - base; if (m > MCHUNK) m = MCHUNK;
  for (int i = t; i < 1024; i += 256) bcnt[i] = 0;
  __syncthreads();
  uint32_t pk[16]; short bn[16];
#pragma unroll
  for (int j = 0; j < 16; j++) {
    int i = base + t + j * 256;
    if (i < base + m) {
      int d = __builtin_nontemporal_load(&dst[i]);
      int s = __builtin_nontemporal_load(&src[i]);
      int b = d >> LBITS;
      pk[j] = ((uint32_t)(d & ((1 << LBITS) - 1)) << SBITS) | (uint32_t)s;
      bn[j] = (short)b;
      atomicAdd(&bcnt[b], 1);
    } else bn[j] = -1;
  }
  __syncthreads();
  {
    int lane = t & 63, w = t >> 6, i0 = t * 4;
    int v0 = bcnt[i0], v1 = bcnt[i0 + 1], v2 = bcnt[i0 + 2], v3 = bcnt[i0 + 3];
    int ts = v0 + v1 + v2 + v3, sc = ts;
    for (int d = 1; d < 64; d <<= 1) { int x = __shfl_up(sc, d, 64); if (lane >= d) sc += x; }
    if (lane == 63) wsum[w] = sc;
    __syncthreads();
    int wo = 0;
    for (int k = 0; k < w; k++) wo += wsum[k];
    int excl = wo + sc - ts;
    boff[i0] = excl; boff[i0 + 1] = excl + v0;
    boff[i0 + 2] = excl + v0 + v1; boff[i0 + 3] = excl + v0 + v1 + v2;
  }
  __syncthreads();
  for (int i = t; i < nbin; i += 256) {
    int c = bcnt[i];
    gbase[i] = c ? atomicAdd(&gcur[i], c) : 0;
  }
  __syncthreads();
  for (int i = t; i < nbin; i += 256) bcnt[i] = boff[i];
  __syncthreads();
#pragma unroll
  for (int j = 0; j < 16; j++) {
    if (bn[j] >= 0) {
      int p = atomicAdd(&bcnt[bn[j]], 1);
      sv[p] = pk[j];
      sb[p] = (uint16_t)bn[j];
    }
  }
  __syncthreads();
  for (int i = t; i < m; i += 256) {
    int b = sb[i];
    int gp = gbase[b] + (i - boff[b]);
    if (gp < (b + 1) * CAPB) bdata[gp] = sv[i];
  }
}

// fused btot + scan (single block, nbin <= 1024)
__global__ void bucket_meta_kernel(const int* __restrict__ gcur, int* __restrict__ bstart,
                                   int nbin, int CAPB) {
  __shared__ int wsum[4];
  int t = threadIdx.x, lane = t & 63, w = t >> 6, i0 = t * 4;
  int v[4];
#pragma unroll
  for (int q = 0; q < 4; q++) {
    int i = i0 + q;
    int c = 0;
    if (i < nbin) {
      c = gcur[i] - i * CAPB;
      if (c > CAPB) c = CAPB;
    }
    v[q] = c;
  }
  int ts = v[0] + v[1] + v[2] + v[3], sc = ts;
  for (int d = 1; d < 64; d <<= 1) { int x = __shfl_up(sc, d, 64); if (lane >= d) sc += x; }
  if (lane == 63) wsum[w] = sc;
  __syncthreads();
  int wo = 0;
  for (int k = 0; k < w; k++) wo += wsum[k];
  int excl = wo + sc - ts;
  int e[4] = {excl, excl + v[0], excl + v[0] + v[1], excl + v[0] + v[1] + v[2]};
#pragma unroll
  for (int q = 0; q < 4; q++)
    if (i0 + q < nbin) bstart[i0 + q] = e[q];
  if (t == 255) bstart[nbin] = wo + sc;
}

// Pass B: counting sort by key (local_dst<<3 | src_chunk); emits off/dis/rdis/csr
__global__ void radixB_kernel(const uint32_t* __restrict__ bdata, const int* __restrict__ gcur,
                              const int* __restrict__ bstart, int CAPB,
                              int* __restrict__ off, float* __restrict__ dis,
                              float* __restrict__ rdis, int* __restrict__ csr,
                              int N, int E, int cshift) {
  __shared__ int cnt[4096], loff[4096];
  __shared__ int wsum[4];
  int b = blockIdx.x, t = threadIdx.x;
  int cb = gcur[b] - b * CAPB; if (cb > CAPB) cb = CAPB;
  int gb = bstart[b];
  const uint32_t* bd = bdata + (size_t)b * CAPB;
  for (int i = t; i < 4096; i += 256) cnt[i] = 0;
  __syncthreads();
  const uint32_t smask = (1u << SBITS) - 1;
  for (int i = t; i < cb; i += 256) {
    uint32_t v = bd[i];
    int ld = v >> SBITS;
    int src = (int)(v & smask);
    atomicAdd(&cnt[(ld << 3) | (src >> cshift)], 1);
  }
  __syncthreads();
  int lane = t & 63, w = t >> 6;
  int loc[16];
  int s = 0;
  int base16 = t * 16;
#pragma unroll
  for (int q = 0; q < 16; q++) { loc[q] = cnt[base16 + q]; s += loc[q]; }
  int sc = s;
  for (int d = 1; d < 64; d <<= 1) { int x = __shfl_up(sc, d, 64); if (lane >= d) sc += x; }
  if (lane == 63) wsum[w] = sc;
  __syncthreads();
  int wo = 0;
  for (int k = 0; k < w; k++) wo += wsum[k];
  int excl = wo + sc - s;
  {
    int run = excl;
#pragma unroll
    for (int q = 0; q < 16; q++) { loff[base16 + q] = run; run += loc[q]; }
  }
  int c0 = loc[0] + loc[1] + loc[2] + loc[3] + loc[4] + loc[5] + loc[6] + loc[7];
  int c1 = loc[8] + loc[9] + loc[10] + loc[11] + loc[12] + loc[13] + loc[14] + loc[15];
  int dst0 = b * (1 << LBITS) + 2 * t;
  if (dst0 < N) {
    off[dst0] = gb + excl;
    dis[dst0] = rsqrtf((float)c0 + 1.0f);
    rdis[dst0] = sqrtf((float)c0 + 1.0f);
  }
  if (dst0 + 1 < N) {
    off[dst0 + 1] = gb + excl + c0;
    dis[dst0 + 1] = rsqrtf((float)c1 + 1.0f);
    rdis[dst0 + 1] = sqrtf((float)c1 + 1.0f);
  }
  if (b == 0 && t == 0) off[N] = E;
  __syncthreads();
  for (int i = t; i < 4096; i += 256) cnt[i] = loff[i];
  __syncthreads();
  for (int i = t; i < cb; i += 256) {
    uint32_t v = bd[i];
    int ld = v >> SBITS;
    int src = (int)(v & smask);
    int p = atomicAdd(&cnt[(ld << 3) | (src >> cshift)], 1);
    csr[gb + p] = src;
  }
}

// ---------------- scan machinery (fallback path) ----------------
__global__ void scan1_kernel(const int* __restrict__ cnt, int* __restrict__ off,
                             int* __restrict__ bsum, float* __restrict__ dis, int N) {
  __shared__ int wsum[4];
  int t = threadIdx.x, lane = t & 63, w = t >> 6;
  int base = blockIdx.x * 1024 + t * 4;
  int v0 = (base + 0 < N) ? cnt[base + 0] : 0;
  int v1 = (base + 1 < N) ? cnt[base + 1] : 0;
  int v2 = (base + 2 < N) ? cnt[base + 2] : 0;
  int v3 = (base + 3 < N) ? cnt[base + 3] : 0;
  if (dis) {
    if (base + 0 < N) dis[base + 0] = rsqrtf((float)v0 + 1.0f);
    if (base + 1 < N) dis[base + 1] = rsqrtf((float)v1 + 1.0f);
    if (base + 2 < N) dis[base + 2] = rsqrtf((float)v2 + 1.0f);
    if (base + 3 < N) dis[base + 3] = rsqrtf((float)v3 + 1.0f);
  }
  int ts = v0 + v1 + v2 + v3;
  int sc = ts;
  for (int d = 1; d < 64; d <<= 1) {
    int x = __shfl_up(sc, d, 64);
    if (lane >= d) sc += x;
  }
  if (lane == 63) wsum[w] = sc;
  __syncthreads();
  int wo = 0;
  for (int i = 0; i < w; i++) wo += wsum[i];
  int excl = wo + sc - ts;
  if (base + 0 < N) off[base + 0] = excl;
  if (base + 1 < N) off[base + 1] = excl + v0;
  if (base + 2 < N) off[base + 2] = excl + v0 + v1;
  if (base + 3 < N) off[base + 3] = excl + v0 + v1 + v2;
  if (t == 255) bsum[blockIdx.x] = wo + sc;
}

__global__ void scan2_kernel(int* __restrict__ bsum, int nb) {
  if (threadIdx.x == 0 && blockIdx.x == 0) {
    int run = 0;
    for (int i = 0; i < nb; i++) { int v = bsum[i]; bsum[i] = run; run += v; }
  }
}

__global__ void scan3_kernel(int* __restrict__ off, const int* __restrict__ bsum,
                             int* __restrict__ cur, int N, int E) {
  int i = blockIdx.x * blockDim.x + threadIdx.x;
  if (i < N) {
    int o = off[i] + bsum[i >> 10];
    off[i] = o;
    if (cur) cur[i] = o;
  }
  if (i == 0) off[N] = E;
}

__global__ void hist_part_kernel(const int* __restrict__ dst, int* __restrict__ cnt,
                                 int E, int N) {
  int p = blockIdx.x & (NPART - 1);
  int chunk = blockIdx.x >> 3;
  int lo = (int)((long long)p * N / NPART);
  int hi = (int)((long long)(p + 1) * N / NPART);
  int stride = NCHUNK * 256;
  for (int e = chunk * 256 + threadIdx.x; e < E; e += stride) {
    int d = __builtin_nontemporal_load(&dst[e]);
    if (d >= lo && d < hi) atomicAdd(&cnt[d], 1);
  }
}

__global__ void fill_part_kernel(const int* __restrict__ src, const int* __restrict__ dst,
                                 int* __restrict__ cur, int* __restrict__ csr, int E, int N) {
  int p = blockIdx.x & (NPART - 1);
  int chunk = blockIdx.x >> 3;
  int lo = (int)((long long)p * N / NPART);
  int hi = (int)((long long)(p + 1) * N / NPART);
  int stride = NCHUNK * 256;
  for (int e = chunk * 256 + threadIdx.x; e < E; e += stride) {
    int d = __builtin_nontemporal_load(&dst[e]);
    if (d >= lo && d < hi) {
      int s = __builtin_nontemporal_load(&src[e]);
      int pos = atomicAdd(&cur[d], 1);
      csr[pos] = s;
    }
  }
}

// ---------------- layer 0 aggregation (scalar csr loads) ----------------
__global__ void l0_agg_kernel(const float4* __restrict__ h0s, const float* __restrict__ dis,
                              const int* __restrict__ off, const int* __restrict__ csr,
                              float* __restrict__ cvec, int N) {
  int n = blockIdx.x * blockDim.x + threadIdx.x;
  if (n >= N) return;
  float4 a = h0s[n];
  int e0 = off[n], e1 = off[n + 1];
  int i = e0;
  for (; i < e1 && (i & 3); i++) {
    float4 v = h0s[csr[i]];
    a.x += v.x; a.y += v.y; a.z += v.z; a.w += v.w;
  }
  for (; i + 4 <= e1; i += 4) {
    int4 c = *(const int4*)&csr[i];
    float4 v0 = h0s[c.x], v1 = h0s[c.y], v2 = h0s[c.z], v3 = h0s[c.w];
    a.x += v0.x + v1.x + v2.x + v3.x;
    a.y += v0.y + v1.y + v2.y + v3.y;
    a.z += v0.z + v1.z + v2.z + v3.z;
    a.w += v0.w + v1.w + v2.w + v3.w;
  }
  for (; i < e1; i++) {
    float4 v = h0s[csr[i]];
    a.x += v.x; a.y += v.y; a.z += v.z; a.w += v.w;
  }
  float dn = dis[n];
  float* cv = cvec + (size_t)n * 8;
  cv[0] = dn * a.x; cv[1] = dn * a.y; cv[2] = dn * a.z; cv[3] = dn * a.w;
}

// h1 = relu(...); writes hb (bf16 dis*h1) and optionally f32 h1 (fallback)
__global__ void l0_combine_kernel(const float* __restrict__ cvec, const float* __restrict__ W0,
                                  const float* __restrict__ b0, const float* __restrict__ resW,
                                  const float* __restrict__ resb, const float* __restrict__ dis,
                                  float* __restrict__ h1, __hip_bfloat16* __restrict__ hbout) {
  int idx = blockIdx.x * blockDim.x + threadIdx.x;
  int n = idx >> 7, c = idx & 127;
  const float* cv = cvec + (size_t)n * 8;
  float acc = b0[c] + resb[c];
#pragma unroll
  for (int k = 0; k < 4; k++) {
    acc += cv[k] * W0[k * HID + c];
    acc += cv[4 + k] * resW[k * HID + c];
  }
  float v = fmaxf(acc, 0.0f);
  if (h1) h1[idx] = v;
  if (hbout) hbout[idx] = __float2bfloat16(dis[n] * v);
}

// ---------------- 128-dim aggregation: scalar (SGPR) csr indices + pk-f32 accumulate ----------------
#define ACC2(W) { f2 v; v.x = __uint_as_float((W) << 16); \
                  v.y = __uint_as_float((W) & 0xffff0000u); a += v; }
__global__ void __launch_bounds__(256, 8)
agg_hid_bf16_kernel(const uint32_t* __restrict__ hb, const float* __restrict__ dis,
                    const int* __restrict__ off, const int* __restrict__ csr,
                    float* __restrict__ out, int N) {
  int node = blockIdx.x * 4 + (threadIdx.x >> 6);
  int lane = threadIdx.x & 63;
  if (node >= N) return;
  uint32_t w = hb[(size_t)node * 64 + lane];
  f2 a;
  a.x = __uint_as_float(w << 16);
  a.y = __uint_as_float(w & 0xffff0000u);
  // wave-uniform bounds -> force into SGPRs so csr index loads go down the scalar path
  int e0 = __builtin_amdgcn_readfirstlane(off[node]);
  int e1 = __builtin_amdgcn_readfirstlane(off[node + 1]);
  int i = e0;
  for (; i < e1 && (i & 3); i++) {
    int s = __builtin_amdgcn_readfirstlane(csr[i]);
    uint32_t ww = hb[(size_t)s * 64 + lane];
    ACC2(ww)
  }
  for (; i + 8 <= e1; i += 8) {
    int4 c0 = *(const int4*)&csr[i];
    int4 c1 = *(const int4*)&csr[i + 4];
    int s0 = __builtin_amdgcn_readfirstlane(c0.x);
    int s1 = __builtin_amdgcn_readfirstlane(c0.y);
    int s2 = __builtin_amdgcn_readfirstlane(c0.z);
    int s3 = __builtin_amdgcn_readfirstlane(c0.w);
    int s4 = __builtin_amdgcn_readfirstlane(c1.x);
    int s5 = __builtin_amdgcn_readfirstlane(c1.y);
    int s6 = __builtin_amdgcn_readfirstlane(c1.z);
    int s7 = __builtin_amdgcn_readfirstlane(c1.w);
    uint32_t w0 = hb[(size_t)s0 * 64 + lane];
    uint32_t w1 = hb[(size_t)s1 * 64 + lane];
    uint32_t w2 = hb[(size_t)s2 * 64 + lane];
    uint32_t w3 = hb[(size_t)s3 * 64 + lane];
    uint32_t w4 = hb[(size_t)s4 * 64 + lane];
    uint32_t w5 = hb[(size_t)s5 * 64 + lane];
    uint32_t w6 = hb[(size_t)s6 * 64 + lane];
    uint32_t w7 = hb[(size_t)s7 * 64 + lane];
    ACC2(w0) ACC2(w1) ACC2(w2) ACC2(w3) ACC2(w4) ACC2(w5) ACC2(w6) ACC2(w7)
  }
  for (; i + 4 <= e1; i += 4) {
    int4 c = *(const int4*)&csr[i];
    int s0 = __builtin_amdgcn_readfirstlane(c.x);
    int s1 = __builtin_amdgcn_readfirstlane(c.y);
    int s2 = __builtin_amdgcn_readfirstlane(c.z);
    int s3 = __builtin_amdgcn_readfirstlane(c.w);
    uint32_t w0 = hb[(size_t)s0 * 64 + lane];
    uint32_t w1 = hb[(size_t)s1 * 64 + lane];
    uint32_t w2 = hb[(size_t)s2 * 64 + lane];
    uint32_t w3 = hb[(size_t)s3 * 64 + lane];
    ACC2(w0) ACC2(w1) ACC2(w2) ACC2(w3)
  }
  for (; i < e1; i++) {
    int s = __builtin_amdgcn_readfirstlane(csr[i]);
    uint32_t ww = hb[(size_t)s * 64 + lane];
    ACC2(ww)
  }
  float dn = dis[node];
  *(float2*)&out[(size_t)node * HID + 2 * lane] = make_float2(dn * a.x, dn * a.y);
}

// f32 fallback aggregation
__global__ void agg_hid_kernel(const float* __restrict__ h, const float* __restrict__ dis,
                               const int* __restrict__ off, const int* __restrict__ csr,
                               float* __restrict__ out, int N) {
  int node = blockIdx.x * 4 + (threadIdx.x >> 6);
  int lane = threadIdx.x & 63;
  if (node >= N) return;
  float dn = dis[node];
  const float* hrow = h + (size_t)node * HID;
  float a0 = dn * hrow[lane];
  float a1 = dn * hrow[lane + 64];
  int e0 = off[node], e1 = off[node + 1];
  for (int i = e0; i < e1; i++) {
    int s = csr[i];
    float d = dis[s];
    const float* hs = h + (size_t)s * HID;
    a0 += d * hs[lane];
    a1 += d * hs[lane + 64];
  }
  out[(size_t)node * HID + lane] = dn * a0;
  out[(size_t)node * HID + lane + 64] = dn * a1;
}

// ---------------- h_next = relu(ag @ W + b + hb_res*rdis); emit bf16 only ----------------
__global__ void gemm_resid_relu_kernel(const float* __restrict__ ag,
                                       const __hip_bfloat16* __restrict__ hbres,
                                       const float* __restrict__ rdis,
                                       const float* __restrict__ W, const float* __restrict__ b,
                                       const float* __restrict__ dis,
                                       __hip_bfloat16* __restrict__ hbout, int N) {
  __shared__ float ash[64 * HID];
  int t = threadIdx.x;
  int n0 = blockIdx.x * 64;
  for (int i = t; i < 64 * HID; i += 256) {
    int gn = n0 + (i >> 7);
    ash[i] = (gn < N) ? ag[(size_t)gn * HID + (i & 127)] : 0.0f;
  }
  __syncthreads();
  int tc = t & 31;
  int tn = t >> 5;
  float acc[8][4];
#pragma unroll
  for (int j = 0; j < 8; j++)
#pragma unroll
    for (int q = 0; q < 4; q++) acc[j][q] = 0.0f;

  for (int k = 0; k < HID; k += 4) {
    float4 w0 = *(const float4*)&W[(k + 0) * HID + tc * 4];
    float4 w1 = *(const float4*)&W[(k + 1) * HID + tc * 4];
    float4 w2 = *(const float4*)&W[(k + 2) * HID + tc * 4];
    float4 w3 = *(const float4*)&W[(k + 3) * HID + tc * 4];
#pragma unroll
    for (int j = 0; j < 8; j++) {
      float4 a = *(const float4*)&ash[(tn * 8 + j) * HID + k];
      acc[j][0] += a.x * w0.x + a.y * w1.x + a.z * w2.x + a.w * w3.x;
      acc[j][1] += a.x * w0.y + a.y * w1.y + a.z * w2.y + a.w * w3.y;
      acc[j][2] += a.x * w0.z + a.y * w1.z + a.z * w2.z + a.w * w3.z;
      acc[j][3] += a.x * w0.w + a.y * w1.w + a.z * w2.w + a.w * w3.w;
    }
  }
  float4 bv = *(const float4*)&b[tc * 4];
#pragma unroll
  for (int j = 0; j < 8; j++) {
    int gn = n0 + tn * 8 + j;
    if (gn < N) {
      float rd = rdis[gn];
      uint2 hu = *(const uint2*)&hbres[(size_t)gn * HID + tc * 4];
      float h0v = __uint_as_float(hu.x << 16) * rd;
      float h1v = __uint_as_float(hu.x & 0xffff0000u) * rd;
      float h2v = __uint_as_float(hu.y << 16) * rd;
      float h3v = __uint_as_float(hu.y & 0xffff0000u) * rd;
      float4 o;
      o.x = fmaxf(acc[j][0] + bv.x + h0v, 0.0f);
      o.y = fmaxf(acc[j][1] + bv.y + h1v, 0.0f);
      o.z = fmaxf(acc[j][2] + bv.z + h2v, 0.0f);
      o.w = fmaxf(acc[j][3] + bv.w + h3v, 0.0f);
      float dnn = dis[gn];
      __hip_bfloat162 p01 = __float22bfloat162_rn(make_float2(dnn * o.x, dnn * o.y));
      __hip_bfloat162 p23 = __float22bfloat162_rn(make_float2(dnn * o.z, dnn * o.w));
      *(__hip_bfloat162*)&hbout[(size_t)gn * HID + tc * 4] = p01;
      *(__hip_bfloat162*)&hbout[(size_t)gn * HID + tc * 4 + 2] = p23;
    }
  }
}

// ---------------- layer 2 fused: h3 = relu(ag@W + b + hb_res*rdis); out = h3@fcW + fcb ----------------
__global__ void gemm_resid_fc_kernel(const float* __restrict__ ag,
                                     const __hip_bfloat16* __restrict__ hbres,
                                     const float* __restrict__ rdis,
                                     const float* __restrict__ W, const float* __restrict__ b,
                                     const float* __restrict__ fcW, const float* __restrict__ fcb,
                                     float* __restrict__ out, int N) {
  __shared__ float ash[64 * HID];
  int t = threadIdx.x;
  int n0 = blockIdx.x * 64;
  for (int i = t; i < 64 * HID; i += 256) {
    int gn = n0 + (i >> 7);
    ash[i] = (gn < N) ? ag[(size_t)gn * HID + (i & 127)] : 0.0f;
  }
  __syncthreads();
  int tc = t & 31;
  int tn = t >> 5;
  float acc[8][4];
#pragma unroll
  for (int j = 0; j < 8; j++)
#pragma unroll
    for (int q = 0; q < 4; q++) acc[j][q] = 0.0f;

  for (int k = 0; k < HID; k += 4) {
    float4 w0 = *(const float4*)&W[(k + 0) * HID + tc * 4];
    float4 w1 = *(const float4*)&W[(k + 1) * HID + tc * 4];
    float4 w2 = *(const float4*)&W[(k + 2) * HID + tc * 4];
    float4 w3 = *(const float4*)&W[(k + 3) * HID + tc * 4];
#pragma unroll
    for (int j = 0; j < 8; j++) {
      float4 a = *(const float4*)&ash[(tn * 8 + j) * HID + k];
      acc[j][0] += a.x * w0.x + a.y * w1.x + a.z * w2.x + a.w * w3.x;
      acc[j][1] += a.x * w0.y + a.y * w1.y + a.z * w2.y + a.w * w3.y;
      acc[j][2] += a.x * w0.z + a.y * w1.z + a.z * w2.z + a.w * w3.z;
      acc[j][3] += a.x * w0.w + a.y * w1.w + a.z * w2.w + a.w * w3.w;
    }
  }
  float4 f0 = *(const float4*)&fcW[(tc * 4 + 0) * 4];
  float4 f1 = *(const float4*)&fcW[(tc * 4 + 1) * 4];
  float4 f2 = *(const float4*)&fcW[(tc * 4 + 2) * 4];
  float4 f3 = *(const float4*)&fcW[(tc * 4 + 3) * 4];
  float4 bv = *(const float4*)&b[tc * 4];
  float4 fb = *(const float4*)&fcb[0];
#pragma unroll
  for (int j = 0; j < 8; j++) {
    int gn = n0 + tn * 8 + j;
    float4 o = make_float4(0.f, 0.f, 0.f, 0.f);
    if (gn < N) {
      float rd = rdis[gn];
      uint2 hu = *(const uint2*)&hbres[(size_t)gn * HID + tc * 4];
      o.x = fmaxf(acc[j][0] + bv.x + __uint_as_float(hu.x << 16) * rd, 0.0f);
      o.y = fmaxf(acc[j][1] + bv.y + __uint_as_float(hu.x & 0xffff0000u) * rd, 0.0f);
      o.z = fmaxf(acc[j][2] + bv.z + __uint_as_float(hu.y << 16) * rd, 0.0f);
      o.w = fmaxf(acc[j][3] + bv.w + __uint_as_float(hu.y & 0xffff0000u) * rd, 0.0f);
    }
    float r0 = o.x * f0.x + o.y * f1.x + o.z * f2.x + o.w * f3.x;
    float r1 = o.x * f0.y + o.y * f1.y + o.z * f2.y + o.w * f3.y;
    float r2 = o.x * f0.z + o.y * f1.z + o.z * f2.z + o.w * f3.z;
    float r3 = o.x * f0.w + o.y * f1.w + o.z * f2.w + o.w * f3.w;
#pragma unroll
    for (int d = 1; d < 32; d <<= 1) {
      r0 += __shfl_xor(r0, d, 64);
      r1 += __shfl_xor(r1, d, 64);
      r2 += __shfl_xor(r2, d, 64);
      r3 += __shfl_xor(r3, d, 64);
    }
    if (tc == 0 && gn < N)
      *(float4*)&out[(size_t)gn * 4] =
          make_float4(r0 + fb.x, r1 + fb.y, r2 + fb.z, r3 + fb.w);
  }
}

// ---------------- f32 fallback gemm kernels ----------------
__global__ void gemm_resid_relu_f32_kernel(const float* __restrict__ ag, float* __restrict__ hout,
                                           const float* __restrict__ hres,
                                           const float* __restrict__ W, const float* __restrict__ b,
                                           int N) {
  __shared__ float ash[64 * HID];
  int t = threadIdx.x;
  int n0 = blockIdx.x * 64;
  for (int i = t; i < 64 * HID; i += 256) {
    int gn = n0 + (i >> 7);
    ash[i] = (gn < N) ? ag[(size_t)gn * HID + (i & 127)] : 0.0f;
  }
  __syncthreads();
  int tc = t & 31;
  int tn = t >> 5;
  float acc[8][4];
#pragma unroll
  for (int j = 0; j < 8; j++)
#pragma unroll
    for (int q = 0; q < 4; q++) acc[j][q] = 0.0f;
  for (int k = 0; k < HID; k += 4) {
    float4 w0 = *(const float4*)&W[(k + 0) * HID + tc * 4];
    float4 w1 = *(const float4*)&W[(k + 1) * HID + tc * 4];
    float4 w2 = *(const float4*)&W[(k + 2) * HID + tc * 4];
    float4 w3 = *(const float4*)&W[(k + 3) * HID + tc * 4];
#pragma unroll
    for (int j = 0; j < 8; j++) {
      float4 a = *(const float4*)&ash[(tn * 8 + j) * HID + k];
      acc[j][0] += a.x * w0.x + a.y * w1.x + a.z * w2.x + a.w * w3.x;
      acc[j][1] += a.x * w0.y + a.y * w1.y + a.z * w2.y + a.w * w3.y;
      acc[j][2] += a.x * w0.z + a.y * w1.z + a.z * w2.z + a.w * w3.z;
      acc[j][3] += a.x * w0.w + a.y * w1.w + a.z * w2.w + a.w * w3.w;
    }
  }
  float4 bv = *(const float4*)&b[tc * 4];
#pragma unroll
  for (int j = 0; j < 8; j++) {
    int gn = n0 + tn * 8 + j;
    if (gn < N) {
      float4 hv = *(const float4*)&hres[(size_t)gn * HID + tc * 4];
      float4 o;
      o.x = fmaxf(acc[j][0] + bv.x + hv.x, 0.0f);
      o.y = fmaxf(acc[j][1] + bv.y + hv.y, 0.0f);
      o.z = fmaxf(acc[j][2] + bv.z + hv.z, 0.0f);
      o.w = fmaxf(acc[j][3] + bv.w + hv.w, 0.0f);
      *(float4*)&hout[(size_t)gn * HID + tc * 4] = o;
    }
  }
}

__global__ void gemm_resid_fc_f32_kernel(const float* __restrict__ ag,
                                         const float* __restrict__ hres,
                                         const float* __restrict__ W, const float* __restrict__ b,
                                         const float* __restrict__ fcW, const float* __restrict__ fcb,
                                         float* __restrict__ out, int N) {
  __shared__ float ash[64 * HID];
  int t = threadIdx.x;
  int n0 = blockIdx.x * 64;
  for (int i = t; i < 64 * HID; i += 256) {
    int gn = n0 + (i >> 7);
    ash[i] = (gn < N) ? ag[(size_t)gn * HID + (i & 127)] : 0.0f;
  }
  __syncthreads();
  int tc = t & 31;
  int tn = t >> 5;
  float acc[8][4];
#pragma unroll
  for (int j = 0; j < 8; j++)
#pragma unroll
    for (int q = 0; q < 4; q++) acc[j][q] = 0.0f;
  for (int k = 0; k < HID; k += 4) {
    float4 w0 = *(const float4*)&W[(k + 0) * HID + tc * 4];
    float4 w1 = *(const float4*)&W[(k + 1) * HID + tc * 4];
    float4 w2 = *(const float4*)&W[(k + 2) * HID + tc * 4];
    float4 w3 = *(const float4*)&W[(k + 3) * HID + tc * 4];
#pragma unroll
    for (int j = 0; j < 8; j++) {
      float4 a = *(const float4*)&ash[(tn * 8 + j) * HID + k];
      acc[j][0] += a.x * w0.x + a.y * w1.x + a.z * w2.x + a.w * w3.x;
      acc[j][1] += a.x * w0.y + a.y * w1.y + a.z * w2.y + a.w * w3.y;
      acc[j][2] += a.x * w0.z + a.y * w1.z + a.z * w2.z + a.w * w3.z;
      acc[j][3] += a.x * w0.w + a.y * w1.w + a.z * w2.w + a.w * w3.w;
    }
  }
  float4 f0 = *(const float4*)&fcW[(tc * 4 + 0) * 4];
  float4 f1 = *(const float4*)&fcW[(tc * 4 + 1) * 4];
  float4 f2 = *(const float4*)&fcW[(tc * 4 + 2) * 4];
  float4 f3 = *(const float4*)&fcW[(tc * 4 + 3) * 4];
  float4 bv = *(const float4*)&b[tc * 4];
  float4 fb = *(const float4*)&fcb[0];
#pragma unroll
  for (int j = 0; j < 8; j++) {
    int gn = n0 + tn * 8 + j;
    float4 o = make_float4(0.f, 0.f, 0.f, 0.f);
    if (gn < N) {
      float4 hv = *(const float4*)&hres[(size_t)gn * HID + tc * 4];
      o.x = fmaxf(acc[j][0] + bv.x + hv.x, 0.0f);
      o.y = fmaxf(acc[j][1] + bv.y + hv.y, 0.0f);
      o.z = fmaxf(acc[j][2] + bv.z + hv.z, 0.0f);
      o.w = fmaxf(acc[j][3] + bv.w + hv.w, 0.0f);
    }
    float r0 = o.x * f0.x + o.y * f1.x + o.z * f2.x + o.w * f3.x;
    float r1 = o.x * f0.y + o.y * f1.y + o.z * f2.y + o.w * f3.y;
    float r2 = o.x * f0.z + o.y * f1.z + o.z * f2.z + o.w * f3.z;
    float r3 = o.x * f0.w + o.y * f1.w + o.z * f2.w + o.w * f3.w;
#pragma unroll
    for (int d = 1; d < 32; d <<= 1) {
      r0 += __shfl_xor(r0, d, 64);
      r1 += __shfl_xor(r1, d, 64);
      r2 += __shfl_xor(r2, d, 64);
      r3 += __shfl_xor(r3, d, 64);
    }
    if (tc == 0 && gn < N)
      *(float4*)&out[(size_t)gn * 4] =
          make_float4(r0 + fb.x, r1 + fb.y, r2 + fb.z, r3 + fb.w);
  }
}

// ---------------- host ----------------
extern "C" void kernel_launch(void* const* d_in, const int* in_sizes, int n_in,
                              void* d_out, int out_size, void* d_ws, size_t ws_size,
                              hipStream_t stream) {
  const float* x = (const float*)d_in[0];
  const int* edge = (const int*)d_in[1];
  const void* maskp = d_in[2];
  const float* W0 = (const float*)d_in[3];
  const float* b0 = (const float*)d_in[4];
  const float* resW = (const float*)d_in[5];
  const float* resb = (const float*)d_in[6];
  const float* W1 = (const float*)d_in[7];
  const float* b1 = (const float*)d_in[8];
  const float* W2 = (const float*)d_in[9];
  const float* b2 = (const float*)d_in[10];
  const float* fcW = (const float*)d_in[11];
  const float* fcb = (const float*)d_in[12];
  float* out = (float*)d_out;

  int N = in_sizes[0] / 4;
  int E = in_sizes[1] / 2;
  const int* srcp = edge;
  const int* dstp = edge + E;

  char* ws = (char*)d_ws;
  size_t cursor = 0;
  auto alloc = [&](size_t bytes) { char* p = ws + cursor; cursor += (bytes + 511) & ~(size_t)511; return p; };
  int* flags = (int*)alloc(16);
  int* cnt = (int*)alloc((size_t)N * 4);   // fallback path only
  float* dis = (float*)alloc((size_t)N * 4);
  float* rdis = (float*)alloc((size_t)N * 4);
  int* off = (int*)alloc((size_t)(N + 1) * 4);
  int* bsum = (int*)alloc(1024);
  int nbin = (N + (1 << LBITS) - 1) >> LBITS;
  int* gcur = (int*)alloc((size_t)(nbin + 1) * 4);
  int* bstart = (int*)alloc((size_t)(nbin + 1) * 4);
  int* csr = (int*)alloc((size_t)E * 4);
  float* h0s = (float*)alloc((size_t)N * 4 * 4);
  float* cvec = (float*)alloc((size_t)N * 8 * 4);
  float* buf0 = (float*)alloc((size_t)N * HID * 4);  // agg output (f32) / fallback h
  float* buf1 = (float*)alloc((size_t)N * HID * 4);  // bdata alias / fallback h
  size_t base_cursor = cursor;
  __hip_bfloat16* hb1 = (__hip_bfloat16*)alloc((size_t)N * HID * 2);
  __hip_bfloat16* hb2 = (__hip_bfloat16*)alloc((size_t)N * HID * 2);
  bool use_bf16 = (cursor <= ws_size);
  if (!use_bf16) {
    hb1 = nullptr; hb2 = nullptr;
    if (base_cursor > ws_size) return;
  }

  long long expect = (long long)E / (nbin > 0 ? nbin : 1);
  int CAPB = (int)((((expect * 5) / 4 + 127) / 64) * 64);
  if (CAPB < 256) CAPB = 256;
  size_t bdata_bytes = (size_t)nbin * CAPB * 4;
  bool use_radix = (N <= (1 << SBITS)) && (nbin <= 1024) &&
                   (bdata_bytes <= (size_t)N * HID * 4);
  uint32_t* bdata = (uint32_t*)buf1;

  int cshift = 0;
  while (((N - 1) >> cshift) > (NCH - 1)) cshift++;

  int nThreadsN = (N + 255) / 256;
  int ngemm = (N + 63) / 64;

  hipMemsetAsync(flags, 0, 16, stream);
  detect_mask_kernel<<<256, 256, 0, stream>>>((const unsigned char*)maskp, N, N / 4, flags);

  if (use_radix) {
    init_gcur_kernel<<<(nbin + 255) / 256, 256, 0, stream>>>(gcur, nbin, CAPB);
    radixA_kernel<<<(E + MCHUNK - 1) / MCHUNK, 256, 0, stream>>>(srcp, dstp, gcur, bdata,
                                                                 nbin, CAPB, E);
    bucket_meta_kernel<<<1, 256, 0, stream>>>(gcur, bstart, nbin, CAPB);
    radixB_kernel<<<nbin, 256, 0, stream>>>(bdata, gcur, bstart, CAPB, off, dis, rdis,
                                            csr, N, E, cshift);
  } else {
    hipMemsetAsync(cnt, 0, (size_t)N * 4, stream);
    int nb = (N + 1023) / 1024;
    hist_part_kernel<<<NPART * NCHUNK, 256, 0, stream>>>(dstp, cnt, E, N);
    scan1_kernel<<<nb, 256, 0, stream>>>(cnt, off, bsum, dis, N);
    scan2_kernel<<<1, 64, 0, stream>>>(bsum, nb);
    scan3_kernel<<<nThreadsN, 256, 0, stream>>>(off, bsum, cnt, N, E);
    fill_part_kernel<<<NPART * NCHUNK, 256, 0, stream>>>(srcp, dstp, cnt, csr, E, N);
  }

  expand_mask_h0<<<nThreadsN, 256, 0, stream>>>(maskp, (const float4*)x, flags, dis,
                                                out + (size_t)N * 4, cvec, (float4*)h0s, N);

  // layer 0
  l0_agg_kernel<<<nThreadsN, 256, 0, stream>>>((const float4*)h0s, dis, off, csr, cvec, N);

  if (use_bf16) {
    l0_combine_kernel<<<(N * HID + 255) / 256, 256, 0, stream>>>(cvec, W0, b0, resW, resb, dis,
                                                                 nullptr, hb1);
    agg_hid_bf16_kernel<<<(N + 3) / 4, 256, 0, stream>>>((const uint32_t*)hb1, dis, off, csr,
                                                         buf0, N);
    gemm_resid_relu_kernel<<<ngemm, 256, 0, stream>>>(buf0, hb1, rdis, W1, b1, dis, hb2, N);
    agg_hid_bf16_kernel<<<(N + 3) / 4, 256, 0, stream>>>((const uint32_t*)hb2, dis, off, csr,
                                                         buf0, N);
    gemm_resid_fc_kernel<<<ngemm, 256, 0, stream>>>(buf0, hb2, rdis, W2, b2, fcW, fcb, out, N);
  } else {
    l0_combine_kernel<<<(N * HID + 255) / 256, 256, 0, stream>>>(cvec, W0, b0, resW, resb, dis,
                                                                 buf0, nullptr);
    agg_hid_kernel<<<(N + 3) / 4, 256, 0, stream>>>(buf0, dis, off, csr, buf1, N);
    gemm_resid_relu_f32_kernel<<<ngemm, 256, 0, stream>>>(buf1, buf1, buf0, W1, b1, N);
    agg_hid_kernel<<<(N + 3) / 4, 256, 0, stream>>>(buf1, dis, off, csr, buf0, N);
    gemm_resid_fc_f32_kernel<<<ngemm, 256, 0, stream>>>(buf0, buf1, W2, b2, fcW, fcb, out, N);
  }
}